// Round 1
// baseline (13170.230 us; speedup 1.0000x reference)
//
#include <hip/hip_runtime.h>
#include <hip/hip_bf16.h>

#define BB 256
#define LINES 64
#define NREG 64
#define DD 1024
#define LL 64
#define KK 16
#define FF 1024

constexpr float EPS = 1e-5f;
constexpr float SCALE = 0.03125f; // 1/sqrt(1024)

__device__ __forceinline__ float wred(float v) {
#pragma unroll
  for (int m = 32; m >= 1; m >>= 1) v += __shfl_xor(v, m);
  return v;
}

__device__ __forceinline__ float wmax64(float v) {
#pragma unroll
  for (int m = 32; m >= 1; m >>= 1) v = fmaxf(v, __shfl_xor(v, m));
  return v;
}

__device__ __forceinline__ float ldw(const float* p) { return *p; }
__device__ __forceinline__ float ldw(const __hip_bfloat16* p) { return __bfloat162float(*p); }

// convert w1|w2|w_res (each 1M f32) into contiguous bf16 buffer
__global__ void cvt_kernel(const float* __restrict__ a, const float* __restrict__ b,
                           const float* __restrict__ c, __hip_bfloat16* __restrict__ o) {
  int i = blockIdx.x * blockDim.x + threadIdx.x;
  const float* src = (i < (1 << 20)) ? a : (i < (2 << 20)) ? b : c;
  int off = i & ((1 << 20) - 1);
  o[i] = __float2bfloat16(src[off]);
}

template <typename WT>
__global__ __launch_bounds__(1024) void interp_kernel(
    const float* __restrict__ opcode_probs,  // (B,LINES,2)
    const float* __restrict__ k_write,       // (B,LINES,D)
    const float* __restrict__ q_read,        // (B,LINES,2,D)
    const float* __restrict__ gate,          // (B,LINES,1)
    const float* __restrict__ ln1_g, const float* __restrict__ ln1_b,
    const WT* __restrict__ w1, const float* __restrict__ b1,
    const float* __restrict__ ln2_g, const float* __restrict__ ln2_b,
    const WT* __restrict__ w2, const float* __restrict__ b2,
    const WT* __restrict__ w_res, const float* __restrict__ b_res,
    const float* __restrict__ lno_g, const float* __restrict__ lno_b,
    float* __restrict__ R)  // (B,NREG,D) state, pre-initialized with `registers`
{
  __shared__ float q0s[DD], q1s[DD], kws[DD];
  __shared__ float sc0[NREG], sc1[NREG], scw[NREG];
  __shared__ float at0[NREG], at1[NREG], wv[NREG];
  __shared__ float xn0[DD], xn1[DD];
  __shared__ float mixs[FF];
  __shared__ float val[DD];
  __shared__ float red[64];

  const int b = blockIdx.x;
  const int tid = threadIdx.x;
  const int w = tid >> 6, lane = tid & 63;
  float* Rb = R + (size_t)b * NREG * DD;

  for (int t = 0; t < LINES; ++t) {
    // stage q0,q1,kw into LDS
    const float* qb = q_read + ((size_t)b * LINES + t) * 2 * DD;
    const float* kb = k_write + ((size_t)b * LINES + t) * DD;
    q0s[tid] = qb[tid];
    q1s[tid] = qb[DD + tid];
    kws[tid] = kb[tid];
    __syncthreads();

    // Phase A: scores S0,S1,Skw over 64 registers (wave w owns regs 4w..4w+3)
#pragma unroll
    for (int rr = 0; rr < 4; ++rr) {
      int r = w * 4 + rr;
      const float* Rr = Rb + (size_t)r * DD;
      float a0 = 0.f, a1 = 0.f, aw = 0.f;
#pragma unroll
      for (int j = 0; j < 16; ++j) {
        int d = j * 64 + lane;
        float rv = Rr[d];
        a0 += rv * q0s[d];
        a1 += rv * q1s[d];
        aw += rv * kws[d];
      }
      a0 = wred(a0); a1 = wred(a1); aw = wred(aw);
      if (lane == 0) { sc0[r] = a0 * SCALE; sc1[r] = a1 * SCALE; scw[r] = aw * SCALE; }
    }
    __syncthreads();

    // Phase B: three 64-wide softmaxes (waves 0..2)
    if (w < 3) {
      const float* src = (w == 0) ? sc0 : (w == 1) ? sc1 : scw;
      float* dst = (w == 0) ? at0 : (w == 1) ? at1 : wv;
      float v = src[lane];
      float mx = wmax64(v);
      float e = expf(v - mx);
      float s = wred(e);
      dst[lane] = e / s;
    }
    __syncthreads();

    // Phase C: op_s[q][d] = sum_r attn[q][r]*R[r][d]  (thread owns d)
    float os0 = 0.f, os1 = 0.f;
    {
      int d = tid;
#pragma unroll 4
      for (int r = 0; r < NREG; ++r) {
        float rv = Rb[(size_t)r * DD + d];
        os0 += at0[r] * rv;
        os1 += at1[r] * rv;
      }
    }

    // Phase D: LN1 / LN2 -> xn0, xn1 in LDS
    {
      float s0 = wred(os0), qq0 = wred(os0 * os0);
      float s1 = wred(os1), qq1 = wred(os1 * os1);
      if (lane == 0) { red[w * 4] = s0; red[w * 4 + 1] = qq0; red[w * 4 + 2] = s1; red[w * 4 + 3] = qq1; }
      __syncthreads();
      float S0 = 0, Q0 = 0, S1 = 0, Q1 = 0;
#pragma unroll
      for (int i = 0; i < 16; ++i) { S0 += red[i * 4]; Q0 += red[i * 4 + 1]; S1 += red[i * 4 + 2]; Q1 += red[i * 4 + 3]; }
      float m0 = S0 * (1.f / DD), v0 = fmaxf(Q0 * (1.f / DD) - m0 * m0, 0.f);
      float m1 = S1 * (1.f / DD), v1 = fmaxf(Q1 * (1.f / DD) - m1 * m1, 0.f);
      xn0[tid] = (os0 - m0) * rsqrtf(v0 + EPS) * ln1_g[tid] + ln1_b[tid];
      xn1[tid] = (os1 - m1) * rsqrtf(v1 + EPS) * ln2_g[tid] + ln2_b[tid];
      __syncthreads();
    }

    // Phase E: two GEMVs (thread owns output f): pre1 = xn0@w1+b1, pre2 = xn1@w2+b2
    float p1v, p2v;
    {
      int f = tid;
      p1v = b1[f];
      p2v = b2[f];
      const WT* c1 = w1 + f;
      const WT* c2 = w2 + f;
#pragma unroll 4
      for (int d = 0; d < DD; ++d) {
        p1v += xn0[d] * ldw(c1 + (size_t)d * FF);
        p2v += xn1[d] * ldw(c2 + (size_t)d * FF);
      }
    }

    // Phase F: per-16 softmax + modular digit conv (16-lane shuffle groups)
    {
      int m = lane & 15, basel = lane & ~15;
      float mx1 = p1v, mx2 = p2v;
      for (int msk = 1; msk < 16; msk <<= 1) {
        mx1 = fmaxf(mx1, __shfl_xor(mx1, msk));
        mx2 = fmaxf(mx2, __shfl_xor(mx2, msk));
      }
      float e1 = expf(p1v - mx1), e2 = expf(p2v - mx2);
      float s1 = e1, s2 = e2;
      for (int msk = 1; msk < 16; msk <<= 1) {
        s1 += __shfl_xor(s1, msk);
        s2 += __shfl_xor(s2, msk);
      }
      float x = e1 / s1, y = e2 / s2;
      float addv = 0.f, subv = 0.f;
#pragma unroll
      for (int i = 0; i < 16; ++i) {
        float xi = __shfl(x, basel + i);
        float ya = __shfl(y, basel + ((m - i) & 15));
        float ys = __shfl(y, basel + ((i - m) & 15));
        addv += xi * ya;
        subv += xi * ys;
      }
      const float* pr = opcode_probs + ((size_t)b * LINES + t) * 2;
      mixs[tid] = pr[0] * addv + pr[1] * subv;
    }
    __syncthreads();

    // Phase G: GEMV res (thread owns output d): acc = mix@w_res + b_res
    float acc;
    {
      int d = tid;
      acc = b_res[d];
      const WT* cr = w_res + d;
#pragma unroll 4
      for (int f = 0; f < FF; ++f) acc += mixs[f] * ldw(cr + (size_t)f * DD);
    }

    // Phase H: output LN -> val in LDS
    {
      float s1 = wred(acc), s2 = wred(acc * acc);
      if (lane == 0) { red[w * 2] = s1; red[w * 2 + 1] = s2; }
      __syncthreads();
      float S = 0, Q = 0;
#pragma unroll
      for (int i = 0; i < 16; ++i) { S += red[i * 2]; Q += red[i * 2 + 1]; }
      float mn = S * (1.f / DD), vr = fmaxf(Q * (1.f / DD) - mn * mn, 0.f);
      val[tid] = (acc - mn) * rsqrtf(vr + EPS) * lno_g[tid] + lno_b[tid];
      __syncthreads();
    }

    // Phase I: gated write-back R = R*(1-gw) + gw*val
    {
      float gt = gate[(size_t)b * LINES + t];
      float vv = val[tid];
      int d = tid;
#pragma unroll 4
      for (int r = 0; r < NREG; ++r) {
        float g = gt * wv[r];
        size_t idx = (size_t)r * DD + d;
        Rb[idx] = Rb[idx] * (1.f - g) + g * vv;
      }
    }
    __syncthreads();  // R visible before next iteration's reads
  }
}

extern "C" void kernel_launch(void* const* d_in, const int* in_sizes, int n_in,
                              void* d_out, int out_size, void* d_ws, size_t ws_size,
                              hipStream_t stream) {
  const float* opcode = (const float*)d_in[0];
  const float* registers = (const float*)d_in[1];
  const float* k_write = (const float*)d_in[2];
  const float* q_read = (const float*)d_in[3];
  // d_in[4] = cond_distribution (unused by reference)
  const float* gate = (const float*)d_in[5];
  const float* ln1_g = (const float*)d_in[6];
  const float* ln1_b = (const float*)d_in[7];
  const float* w1 = (const float*)d_in[8];
  const float* b1 = (const float*)d_in[9];
  const float* ln2_g = (const float*)d_in[10];
  const float* ln2_b = (const float*)d_in[11];
  const float* w2 = (const float*)d_in[12];
  const float* b2 = (const float*)d_in[13];
  const float* w_res = (const float*)d_in[14];
  const float* b_res = (const float*)d_in[15];
  const float* lno_g = (const float*)d_in[16];
  const float* lno_b = (const float*)d_in[17];
  float* R = (float*)d_out;

  // R state lives in d_out; initialize from `registers` every launch (deterministic).
  hipMemcpyAsync(R, registers, (size_t)BB * NREG * DD * sizeof(float),
                 hipMemcpyDeviceToDevice, stream);

  const size_t wbytes = (size_t)3 * (1 << 20) * sizeof(__hip_bfloat16);  // 6 MB
  if (ws_size >= wbytes) {
    __hip_bfloat16* wb = (__hip_bfloat16*)d_ws;
    cvt_kernel<<<(3 * (1 << 20)) / 256, 256, 0, stream>>>(w1, w2, w_res, wb);
    interp_kernel<__hip_bfloat16><<<BB, 1024, 0, stream>>>(
        opcode, k_write, q_read, gate, ln1_g, ln1_b, wb, b1, ln2_g, ln2_b,
        wb + (1 << 20), b2, wb + (2 << 20), b_res, lno_g, lno_b, R);
  } else {
    interp_kernel<float><<<BB, 1024, 0, stream>>>(
        opcode, k_write, q_read, gate, ln1_g, ln1_b, w1, b1, ln2_g, ln2_b,
        w2, b2, w_res, b_res, lno_g, lno_b, R);
  }
}

// Round 2
// 10048.791 us; speedup vs baseline: 1.3106x; 1.3106x over previous
//
#include <hip/hip_runtime.h>
#include <hip/hip_bf16.h>

#define BB 256
#define LINES 64
#define NREG 64
#define DD 1024
#define FF 1024

constexpr float EPS = 1e-5f;
constexpr float SCALE = 0.03125f; // 1/sqrt(1024)

typedef __bf16 bf16_t;
typedef bf16_t bf16x8 __attribute__((ext_vector_type(8)));
typedef float f32x4 __attribute__((ext_vector_type(4)));

// ---------------- d_ws layout (bytes) ----------------
#define WS_W1T   0u                         // w1^T  [f][d] bf16, 2MB
#define WS_W2T   (2u << 20)                 // w2^T  [f][d] bf16, 2MB
#define WS_WRT   (4u << 20)                 // w_res^T [d][f] bf16, 2MB
#define WS_XNG   (6u << 20)                 // xng [16g][2][16m][1024] bf16, 1MB
#define WS_MIXG  (7u << 20)                 // mixg [16g][16][1024] bf16, 0.5MB
#define WS_GT    ((7u << 20) + (1u << 19))  // gt  [256][1024] f32, 1MB
#define WS_CTR   ((8u << 20) + (1u << 19))  // 16 counters x 64B
#define WS_NEED  (WS_CTR + 1024u)

// ---------------- LDS layout (bytes) ----------------
#define SM_WV    0
#define SM_AT0   256
#define SM_AT1   512
#define SM_SC0   768
#define SM_SC1   1024
#define SM_SCW   1280
#define SM_RED   1536
#define SM_PB    1792
#define SM_DYN   2048
#define SM_Q0    SM_DYN
#define SM_Q1    (SM_DYN + 4096)
#define SM_KW    (SM_DYN + 8192)
#define SM_ATILE SM_DYN                     // 32KB bf16 [16][1024] XOR-swizzled
#define SM_RED2  (SM_DYN + 32768)           // [3][4][16][17] f32 = 13056B
#define SM_PRE   (SM_DYN + 32768 + 13056)   // [2][16][66] f32 = 8448B
#define SM_SIZE  (SM_DYN + 32768 + 13056 + 8448)

__device__ __forceinline__ float wred(float v) {
#pragma unroll
  for (int m = 32; m >= 1; m >>= 1) v += __shfl_xor(v, m);
  return v;
}
__device__ __forceinline__ float wmax64(float v) {
#pragma unroll
  for (int m = 32; m >= 1; m >>= 1) v = fmaxf(v, __shfl_xor(v, m));
  return v;
}
__device__ __forceinline__ float lane_bcast(float v, int r) {
  return __builtin_bit_cast(float, __builtin_amdgcn_readlane(__builtin_bit_cast(int, v), r));
}

__device__ __forceinline__ void group_barrier(unsigned* ctr, int tid, unsigned target) {
  __syncthreads();  // drains vmcnt for all threads' global writes
  if (tid == 0) {
    __threadfence();  // release: L2 writeback (agent scope)
    __hip_atomic_fetch_add(ctr, 1u, __ATOMIC_RELEASE, __HIP_MEMORY_SCOPE_AGENT);
    while (__hip_atomic_load(ctr, __ATOMIC_ACQUIRE, __HIP_MEMORY_SCOPE_AGENT) < target)
      __builtin_amdgcn_s_sleep(2);
    __threadfence();  // acquire: invalidate stale L1/L2
  }
  __syncthreads();
}

// transpose + f32->bf16: dst[j][i] = src[i][j], 1024x1024; z selects matrix
__global__ __launch_bounds__(256) void transcvt(const float* __restrict__ w1,
                                                const float* __restrict__ w2,
                                                const float* __restrict__ wr,
                                                bf16_t* __restrict__ out) {
  __shared__ float tl[64][65];
  const float* src = (blockIdx.z == 0) ? w1 : (blockIdx.z == 1) ? w2 : wr;
  bf16_t* dst = out + (size_t)blockIdx.z * (1u << 20);
  const int i0 = blockIdx.x * 64, j0 = blockIdx.y * 64;
  const int t = threadIdx.x;
#pragma unroll
  for (int it = 0; it < 4; ++it) {
    int r = (t >> 4) + it * 16;
    int c4 = (t & 15) * 4;
    const float4 v = *reinterpret_cast<const float4*>(&src[(size_t)(i0 + r) * 1024 + j0 + c4]);
    tl[r][c4] = v.x; tl[r][c4 + 1] = v.y; tl[r][c4 + 2] = v.z; tl[r][c4 + 3] = v.w;
  }
  __syncthreads();
  const int orow = t >> 2, seg = t & 3;
  bf16x8 v0, v1;
#pragma unroll
  for (int u = 0; u < 8; ++u) {
    v0[u] = (bf16_t)tl[seg * 16 + u][orow];
    v1[u] = (bf16_t)tl[seg * 16 + 8 + u][orow];
  }
  bf16_t* dp = dst + (size_t)(j0 + orow) * 1024 + i0 + seg * 16;
  *reinterpret_cast<bf16x8*>(dp) = v0;
  *reinterpret_cast<bf16x8*>(dp + 8) = v1;
}

__global__ __launch_bounds__(1024) void interp2(
    const float* __restrict__ opcode_probs, const float* __restrict__ k_write,
    const float* __restrict__ q_read, const float* __restrict__ gate,
    const float* __restrict__ ln1_g, const float* __restrict__ ln1_b, const float* __restrict__ b1,
    const float* __restrict__ ln2_g, const float* __restrict__ ln2_b, const float* __restrict__ b2,
    const float* __restrict__ b_res, const float* __restrict__ lno_g, const float* __restrict__ lno_b,
    char* __restrict__ ws, float* __restrict__ R) {
  __shared__ __align__(16) char smem[SM_SIZE];
  float* wvp  = (float*)(smem + SM_WV);
  float* at0p = (float*)(smem + SM_AT0);
  float* at1p = (float*)(smem + SM_AT1);
  float* sc0p = (float*)(smem + SM_SC0);
  float* sc1p = (float*)(smem + SM_SC1);
  float* scwp = (float*)(smem + SM_SCW);
  float* redp = (float*)(smem + SM_RED);
  float* pbp  = (float*)(smem + SM_PB);
  float* q0p  = (float*)(smem + SM_Q0);
  float* q1p  = (float*)(smem + SM_Q1);
  float* kwp  = (float*)(smem + SM_KW);

  const int b = blockIdx.x;
  const int g = b & 15, m = b >> 4;
  const int q = g * 16 + m;              // batch owned for per-batch phases
  const int tid = threadIdx.x;
  const int w = tid >> 6, lane = tid & 63;
  const int ln15 = lane & 15, kgrp = lane >> 4;

  const bf16_t* w1t = (const bf16_t*)(ws + WS_W1T);
  const bf16_t* w2t = (const bf16_t*)(ws + WS_W2T);
  const bf16_t* wrt = (const bf16_t*)(ws + WS_WRT);
  bf16_t* xng  = (bf16_t*)(ws + WS_XNG);
  bf16_t* mixg = (bf16_t*)(ws + WS_MIXG);
  float*  gtb  = (float*)(ws + WS_GT);
  unsigned* ctr = (unsigned*)(ws + WS_CTR) + g * 16;

  float* Rb = R + (size_t)q * (NREG * DD);
  unsigned nbar = 0;

  for (int t = 0; t < LINES; ++t) {
    // ---- Phase A: stage q0,q1,kw; attention scores ----
    const float* qb = q_read + ((size_t)q * LINES + t) * (2 * DD);
    const float* kb = k_write + ((size_t)q * LINES + t) * DD;
    q0p[tid] = qb[tid];
    q1p[tid] = qb[DD + tid];
    kwp[tid] = kb[tid];
    if (tid == 0) pbp[0] = gate[(size_t)q * LINES + t];
    __syncthreads();
#pragma unroll
    for (int rr = 0; rr < 4; ++rr) {
      int r = w * 4 + rr;
      const float* Rr = Rb + (size_t)r * DD;
      float a0 = 0.f, a1 = 0.f, aw = 0.f;
#pragma unroll
      for (int j = 0; j < 16; ++j) {
        int d = j * 64 + lane;
        float rv = Rr[d];
        a0 = fmaf(rv, q0p[d], a0);
        a1 = fmaf(rv, q1p[d], a1);
        aw = fmaf(rv, kwp[d], aw);
      }
      a0 = wred(a0); a1 = wred(a1); aw = wred(aw);
      if (lane == 0) { sc0p[r] = a0 * SCALE; sc1p[r] = a1 * SCALE; scwp[r] = aw * SCALE; }
    }
    __syncthreads();
    // ---- Phase B: three 64-wide softmaxes ----
    if (w < 3) {
      const float* src = (w == 0) ? sc0p : (w == 1) ? sc1p : scwp;
      float* dst = (w == 0) ? at0p : (w == 1) ? at1p : wvp;
      float v = src[lane];
      float mx = wmax64(v);
      float e = expf(v - mx);
      float s = wred(e);
      dst[lane] = e / s;
    }
    __syncthreads();
    // ---- Phase C: op_s (thread owns d=tid) ----
    float a0r = at0p[lane], a1r = at1p[lane];
    float os0 = 0.f, os1 = 0.f;
#pragma unroll 8
    for (int r = 0; r < NREG; ++r) {
      float rv = Rb[(size_t)r * DD + tid];
      os0 = fmaf(lane_bcast(a0r, r), rv, os0);
      os1 = fmaf(lane_bcast(a1r, r), rv, os1);
    }
    // ---- Phase D: LN1/LN2 -> xng (bf16, global scratch) ----
    {
      float s0 = wred(os0), qq0 = wred(os0 * os0);
      float s1 = wred(os1), qq1 = wred(os1 * os1);
      if (lane == 0) { redp[w*4] = s0; redp[w*4+1] = qq0; redp[w*4+2] = s1; redp[w*4+3] = qq1; }
      __syncthreads();
      float S0 = 0, Q0 = 0, S1 = 0, Q1 = 0;
#pragma unroll
      for (int i = 0; i < 16; ++i) { S0 += redp[i*4]; Q0 += redp[i*4+1]; S1 += redp[i*4+2]; Q1 += redp[i*4+3]; }
      float m0 = S0 * (1.f / DD), v0 = fmaxf(Q0 * (1.f / DD) - m0 * m0, 0.f);
      float m1 = S1 * (1.f / DD), v1 = fmaxf(Q1 * (1.f / DD) - m1 * m1, 0.f);
      float xn0v = (os0 - m0) * rsqrtf(v0 + EPS) * ln1_g[tid] + ln1_b[tid];
      float xn1v = (os1 - m1) * rsqrtf(v1 + EPS) * ln2_g[tid] + ln2_b[tid];
      xng[(((size_t)g * 2 + 0) * 16 + m) * DD + tid] = (bf16_t)xn0v;
      xng[(((size_t)g * 2 + 1) * 16 + m) * DD + tid] = (bf16_t)xn1v;
    }
    group_barrier(ctr, tid, 16u * (++nbar));   // bar_A: xng ready

    // ---- Phase E: two 16x1024 @ 1024x64 MFMA GEMMs (f-slice of this block) ----
    for (int gm = 0; gm < 2; ++gm) {
      const uint4* asrc = (const uint4*)(xng + ((size_t)g * 2 + gm) * (16 * DD));
#pragma unroll
      for (int c = 0; c < 2; ++c) {
        int ch = tid + c * 1024;
        int row = ch >> 7, k16 = ch & 127;
        unsigned byte = (unsigned)(row * 2048 + k16 * 16) ^ ((unsigned)(row & 7) << 4);
        *(uint4*)(smem + SM_ATILE + byte) = asrc[ch];
      }
      __syncthreads();
      const int ns = w & 3, ks = w >> 2;          // 4 n-subtiles x 4 k-splits
      const bf16_t* bsrc = (gm ? w2t : w1t) + (size_t)(64 * m + ns * 16 + ln15) * DD;
      f32x4 acc = {0.f, 0.f, 0.f, 0.f};
#pragma unroll
      for (int kc = 0; kc < 8; ++kc) {
        int kb = ks * 256 + kc * 32 + kgrp * 8;
        unsigned abyte = ((unsigned)(ln15 * 2048 + kb * 2)) ^ ((unsigned)(ln15 & 7) << 4);
        bf16x8 av = *(const bf16x8*)(smem + SM_ATILE + abyte);
        bf16x8 bv = *(const bf16x8*)(bsrc + kb);
        acc = __builtin_amdgcn_mfma_f32_16x16x32_bf16(av, bv, acc, 0, 0, 0);
      }
      __syncthreads();
      float* red2 = (float*)(smem + SM_RED2);
      if (ks > 0) {
#pragma unroll
        for (int r2 = 0; r2 < 4; ++r2)
          red2[((ks - 1) * 4 + ns) * (16 * 17) + (kgrp * 4 + r2) * 17 + ln15] = acc[r2];
      }
      __syncthreads();
      if (ks == 0) {
        float* prep = (float*)(smem + SM_PRE) + gm * (16 * 66);
#pragma unroll
        for (int r2 = 0; r2 < 4; ++r2) {
          int crow = kgrp * 4 + r2;
          float v = acc[r2];
#pragma unroll
          for (int kk = 0; kk < 3; ++kk)
            v += red2[(kk * 4 + ns) * (16 * 17) + crow * 17 + ln15];
          prep[crow * 66 + ns * 16 + ln15] = v;
        }
      }
      __syncthreads();
    }
    // ---- Phase F: per-16 softmax + modular digit conv; wave w = batch-row w ----
    {
      float* prep = (float*)(smem + SM_PRE);
      const int bb2 = w, c = lane;
      float xp = prep[bb2 * 66 + c] + b1[64 * m + c];
      float yp = prep[16 * 66 + bb2 * 66 + c] + b2[64 * m + c];
      float mx1 = xp, mx2 = yp;
#pragma unroll
      for (int msk = 1; msk < 16; msk <<= 1) {
        mx1 = fmaxf(mx1, __shfl_xor(mx1, msk));
        mx2 = fmaxf(mx2, __shfl_xor(mx2, msk));
      }
      float e1 = expf(xp - mx1), e2 = expf(yp - mx2);
      float s1 = e1, s2 = e2;
#pragma unroll
      for (int msk = 1; msk < 16; msk <<= 1) {
        s1 += __shfl_xor(s1, msk);
        s2 += __shfl_xor(s2, msk);
      }
      float x = e1 / s1, y = e2 / s2;
      int mm = lane & 15, basel = lane & ~15;
      float addv = 0.f, subv = 0.f;
#pragma unroll
      for (int i = 0; i < 16; ++i) {
        float xi = __shfl(x, basel + i);
        float ya = __shfl(y, basel + ((mm - i) & 15));
        float ys = __shfl(y, basel + ((i - mm) & 15));
        addv = fmaf(xi, ya, addv);
        subv = fmaf(xi, ys, subv);
      }
      int q2 = g * 16 + bb2;
      const float* pr = opcode_probs + ((size_t)q2 * LINES + t) * 2;
      float mix = pr[0] * addv + pr[1] * subv;
      mixg[((size_t)g * 16 + bb2) * DD + 64 * m + c] = (bf16_t)mix;
    }
    group_barrier(ctr, tid, 16u * (++nbar));   // bar_B: mix ready

    // ---- Phase G: mix(16x1024) @ w_res(1024x1024), d-slice of this block ----
    {
      const uint4* asrc = (const uint4*)(mixg + (size_t)g * (16 * DD));
#pragma unroll
      for (int c = 0; c < 2; ++c) {
        int ch = tid + c * 1024;
        int row = ch >> 7, k16 = ch & 127;
        unsigned byte = (unsigned)(row * 2048 + k16 * 16) ^ ((unsigned)(row & 7) << 4);
        *(uint4*)(smem + SM_ATILE + byte) = asrc[ch];
      }
      __syncthreads();
      const int ns = w & 3, ks = w >> 2;
      const bf16_t* bsrc = wrt + (size_t)(64 * m + ns * 16 + ln15) * DD;
      f32x4 acc = {0.f, 0.f, 0.f, 0.f};
#pragma unroll
      for (int kc = 0; kc < 8; ++kc) {
        int kb = ks * 256 + kc * 32 + kgrp * 8;
        unsigned abyte = ((unsigned)(ln15 * 2048 + kb * 2)) ^ ((unsigned)(ln15 & 7) << 4);
        bf16x8 av = *(const bf16x8*)(smem + SM_ATILE + abyte);
        bf16x8 bv = *(const bf16x8*)(bsrc + kb);
        acc = __builtin_amdgcn_mfma_f32_16x16x32_bf16(av, bv, acc, 0, 0, 0);
      }
      __syncthreads();
      float* red2 = (float*)(smem + SM_RED2);
      if (ks > 0) {
#pragma unroll
        for (int r2 = 0; r2 < 4; ++r2)
          red2[((ks - 1) * 4 + ns) * (16 * 17) + (kgrp * 4 + r2) * 17 + ln15] = acc[r2];
      }
      __syncthreads();
      if (ks == 0) {
        int f = 64 * m + ns * 16 + ln15;
#pragma unroll
        for (int r2 = 0; r2 < 4; ++r2) {
          int crow = kgrp * 4 + r2;
          float v = acc[r2];
#pragma unroll
          for (int kk = 0; kk < 3; ++kk)
            v += red2[(kk * 4 + ns) * (16 * 17) + crow * 17 + ln15];
          gtb[((size_t)g * 16 + crow) * DD + f] = v + b_res[f];
        }
      }
    }
    group_barrier(ctr, tid, 16u * (++nbar));   // bar_C: gt ready

    // ---- Phase H: output LN (thread owns d=tid, own batch row) ----
    float vv;
    {
      float xv = gtb[((size_t)g * 16 + m) * DD + tid];
      float s1 = wred(xv), s2 = wred(xv * xv);
      if (lane == 0) { redp[w * 2] = s1; redp[w * 2 + 1] = s2; }
      __syncthreads();
      float S = 0.f, Q = 0.f;
#pragma unroll
      for (int i = 0; i < 16; ++i) { S += redp[i * 2]; Q += redp[i * 2 + 1]; }
      float mn = S * (1.f / DD), vr = fmaxf(Q * (1.f / DD) - mn * mn, 0.f);
      vv = (xv - mn) * rsqrtf(vr + EPS) * lno_g[tid] + lno_b[tid];
    }
    // ---- Phase I: gated write-back (block-local R) ----
    {
      float wvreg = wvp[lane];
      float gtv = pbp[0];
#pragma unroll 4
      for (int r = 0; r < NREG; ++r) {
        float gg = gtv * lane_bcast(wvreg, r);
        size_t idx = (size_t)r * DD + tid;
        Rb[idx] = Rb[idx] * (1.f - gg) + gg * vv;
      }
    }
    __syncthreads();
  }
}

// ---------------- fallback (round-1 structure, f32 weights) ----------------
__global__ __launch_bounds__(1024) void interp_fb(
    const float* __restrict__ opcode_probs, const float* __restrict__ k_write,
    const float* __restrict__ q_read, const float* __restrict__ gate,
    const float* __restrict__ ln1_g, const float* __restrict__ ln1_b,
    const float* __restrict__ w1, const float* __restrict__ b1,
    const float* __restrict__ ln2_g, const float* __restrict__ ln2_b,
    const float* __restrict__ w2, const float* __restrict__ b2,
    const float* __restrict__ w_res, const float* __restrict__ b_res,
    const float* __restrict__ lno_g, const float* __restrict__ lno_b,
    float* __restrict__ R) {
  __shared__ float q0s[DD], q1s[DD], kws[DD];
  __shared__ float sc0[NREG], sc1[NREG], scw[NREG];
  __shared__ float at0[NREG], at1[NREG], wv[NREG];
  __shared__ float xn0[DD], xn1[DD];
  __shared__ float mixs[FF];
  __shared__ float val[DD];
  __shared__ float red[64];
  const int b = blockIdx.x;
  const int tid = threadIdx.x;
  const int w = tid >> 6, lane = tid & 63;
  float* Rb = R + (size_t)b * NREG * DD;
  for (int t = 0; t < LINES; ++t) {
    const float* qb = q_read + ((size_t)b * LINES + t) * 2 * DD;
    const float* kb = k_write + ((size_t)b * LINES + t) * DD;
    q0s[tid] = qb[tid]; q1s[tid] = qb[DD + tid]; kws[tid] = kb[tid];
    __syncthreads();
#pragma unroll
    for (int rr = 0; rr < 4; ++rr) {
      int r = w * 4 + rr;
      const float* Rr = Rb + (size_t)r * DD;
      float a0 = 0.f, a1 = 0.f, aw = 0.f;
#pragma unroll
      for (int j = 0; j < 16; ++j) {
        int d = j * 64 + lane;
        float rv = Rr[d];
        a0 += rv * q0s[d]; a1 += rv * q1s[d]; aw += rv * kws[d];
      }
      a0 = wred(a0); a1 = wred(a1); aw = wred(aw);
      if (lane == 0) { sc0[r] = a0 * SCALE; sc1[r] = a1 * SCALE; scw[r] = aw * SCALE; }
    }
    __syncthreads();
    if (w < 3) {
      const float* src = (w == 0) ? sc0 : (w == 1) ? sc1 : scw;
      float* dst = (w == 0) ? at0 : (w == 1) ? at1 : wv;
      float v = src[lane];
      float mx = wmax64(v);
      float e = expf(v - mx);
      float s = wred(e);
      dst[lane] = e / s;
    }
    __syncthreads();
    float os0 = 0.f, os1 = 0.f;
#pragma unroll 4
    for (int r = 0; r < NREG; ++r) {
      float rv = Rb[(size_t)r * DD + tid];
      os0 += at0[r] * rv; os1 += at1[r] * rv;
    }
    {
      float s0 = wred(os0), qq0 = wred(os0 * os0);
      float s1 = wred(os1), qq1 = wred(os1 * os1);
      if (lane == 0) { red[w*4] = s0; red[w*4+1] = qq0; red[w*4+2] = s1; red[w*4+3] = qq1; }
      __syncthreads();
      float S0 = 0, Q0 = 0, S1 = 0, Q1 = 0;
#pragma unroll
      for (int i = 0; i < 16; ++i) { S0 += red[i*4]; Q0 += red[i*4+1]; S1 += red[i*4+2]; Q1 += red[i*4+3]; }
      float m0 = S0 / DD, v0 = fmaxf(Q0 / DD - m0 * m0, 0.f);
      float m1 = S1 / DD, v1 = fmaxf(Q1 / DD - m1 * m1, 0.f);
      xn0[tid] = (os0 - m0) * rsqrtf(v0 + EPS) * ln1_g[tid] + ln1_b[tid];
      xn1[tid] = (os1 - m1) * rsqrtf(v1 + EPS) * ln2_g[tid] + ln2_b[tid];
      __syncthreads();
    }
    float p1v = b1[tid], p2v = b2[tid];
    {
      const float* c1 = w1 + tid;
      const float* c2 = w2 + tid;
#pragma unroll 4
      for (int d = 0; d < DD; ++d) {
        p1v += xn0[d] * c1[(size_t)d * FF];
        p2v += xn1[d] * c2[(size_t)d * FF];
      }
    }
    {
      int mmm = lane & 15, basel = lane & ~15;
      float mx1 = p1v, mx2 = p2v;
      for (int msk = 1; msk < 16; msk <<= 1) {
        mx1 = fmaxf(mx1, __shfl_xor(mx1, msk));
        mx2 = fmaxf(mx2, __shfl_xor(mx2, msk));
      }
      float e1 = expf(p1v - mx1), e2 = expf(p2v - mx2);
      float s1 = e1, s2 = e2;
      for (int msk = 1; msk < 16; msk <<= 1) { s1 += __shfl_xor(s1, msk); s2 += __shfl_xor(s2, msk); }
      float x = e1 / s1, y = e2 / s2;
      float addv = 0.f, subv = 0.f;
#pragma unroll
      for (int i = 0; i < 16; ++i) {
        float xi = __shfl(x, basel + i);
        float ya = __shfl(y, basel + ((mmm - i) & 15));
        float ys = __shfl(y, basel + ((i - mmm) & 15));
        addv += xi * ya; subv += xi * ys;
      }
      const float* pr = opcode_probs + ((size_t)b * LINES + t) * 2;
      mixs[tid] = pr[0] * addv + pr[1] * subv;
    }
    __syncthreads();
    float acc = b_res[tid];
    {
      const float* cr = w_res + tid;
#pragma unroll 4
      for (int f = 0; f < FF; ++f) acc += mixs[f] * cr[(size_t)f * DD];
    }
    {
      float s1 = wred(acc), s2 = wred(acc * acc);
      if (lane == 0) { red[w*2] = s1; red[w*2+1] = s2; }
      __syncthreads();
      float S = 0, Q = 0;
#pragma unroll
      for (int i = 0; i < 16; ++i) { S += red[i*2]; Q += red[i*2+1]; }
      float mn = S / DD, vr = fmaxf(Q / DD - mn * mn, 0.f);
      val[tid] = (acc - mn) * rsqrtf(vr + EPS) * lno_g[tid] + lno_b[tid];
      __syncthreads();
    }
    {
      float gt_ = gate[(size_t)b * LINES + t];
      float vv = val[tid];
#pragma unroll 4
      for (int r = 0; r < NREG; ++r) {
        float gg = gt_ * wv[r];
        size_t idx = (size_t)r * DD + tid;
        Rb[idx] = Rb[idx] * (1.f - gg) + gg * vv;
      }
    }
    __syncthreads();
  }
}

extern "C" void kernel_launch(void* const* d_in, const int* in_sizes, int n_in,
                              void* d_out, int out_size, void* d_ws, size_t ws_size,
                              hipStream_t stream) {
  const float* opcode = (const float*)d_in[0];
  const float* registers = (const float*)d_in[1];
  const float* k_write = (const float*)d_in[2];
  const float* q_read = (const float*)d_in[3];
  const float* gate = (const float*)d_in[5];
  const float* ln1_g = (const float*)d_in[6];
  const float* ln1_b = (const float*)d_in[7];
  const float* w1 = (const float*)d_in[8];
  const float* b1 = (const float*)d_in[9];
  const float* ln2_g = (const float*)d_in[10];
  const float* ln2_b = (const float*)d_in[11];
  const float* w2 = (const float*)d_in[12];
  const float* b2 = (const float*)d_in[13];
  const float* w_res = (const float*)d_in[14];
  const float* b_res = (const float*)d_in[15];
  const float* lno_g = (const float*)d_in[16];
  const float* lno_b = (const float*)d_in[17];
  float* R = (float*)d_out;

  hipMemcpyAsync(R, registers, (size_t)BB * NREG * DD * sizeof(float),
                 hipMemcpyDeviceToDevice, stream);

  if (ws_size >= (size_t)WS_NEED) {
    transcvt<<<dim3(16, 16, 3), 256, 0, stream>>>(w1, w2, w_res, (bf16_t*)d_ws);
    hipMemsetAsync((char*)d_ws + WS_CTR, 0, 1024, stream);
    interp2<<<BB, 1024, 0, stream>>>(opcode, k_write, q_read, gate, ln1_g, ln1_b, b1,
                                     ln2_g, ln2_b, b2, b_res, lno_g, lno_b,
                                     (char*)d_ws, R);
  } else {
    interp_fb<<<BB, 1024, 0, stream>>>(opcode, k_write, q_read, gate, ln1_g, ln1_b,
                                       w1, b1, ln2_g, ln2_b, w2, b2, w_res, b_res,
                                       lno_g, lno_b, R);
  }
}

// Round 4
// 6464.085 us; speedup vs baseline: 2.0374x; 1.5546x over previous
//
#include <hip/hip_runtime.h>
#include <hip/hip_bf16.h>

#define BB 256
#define LINES 64
#define NREG 64
#define DD 1024
#define FF 1024

constexpr float EPS = 1e-5f;
constexpr float SCALE = 0.03125f; // 1/sqrt(1024)

typedef __bf16 bf16_t;
typedef bf16_t bf16x8 __attribute__((ext_vector_type(8)));
typedef unsigned short us16x8 __attribute__((ext_vector_type(8)));
typedef float f32x4 __attribute__((ext_vector_type(4)));
typedef unsigned u32x4v __attribute__((ext_vector_type(4)));
typedef unsigned long long u64;

// ---------------- d_ws layout (bytes) ----------------
#define WS_W1T   0u                         // w1^T  [f][d] bf16, 2MB
#define WS_W2T   (2u << 20)                 // w2^T  [f][d] bf16, 2MB
#define WS_WRT   (4u << 20)                 // w_res^T [d][f] bf16, 2MB
#define WS_XNP   (6u << 20)                 // xnp [16g][16m][1024] u32 (bf16 xn0|xn1), 1MB
#define WS_MIXP  (7u << 20)                 // mixp [16g][16][1024] bf16, 512KB
#define WS_GT    ((7u << 20) + (1u << 19))  // gt  [16g][16][1024] f32, 1MB
#define WS_CTR   ((8u << 20) + (1u << 19))  // 16 counters x 64B
#define WS_NEED  (WS_CTR + 1024u)

// ---------------- LDS layout (bytes) ----------------
#define SM_WV    0
#define SM_AT0P  256
#define SM_AT1P  512
#define SM_SC0   768
#define SM_SC1   1024
#define SM_SCW   1280
#define SM_RED   1536
#define SM_PB    1792
#define SM_DYN   2048
#define SM_Q0    SM_DYN
#define SM_Q1    (SM_DYN + 4096)
#define SM_KW    (SM_DYN + 8192)
#define SM_AT0   SM_DYN                     // 32KB bf16 [16][1024] XOR-swizzled (xn0 / mix tile)
#define SM_AT1   (SM_DYN + 32768)           // 32KB tile for xn1
#define SM_RED2  (SM_DYN + 65536)           // [3][4][16][17] f32 = 13056B
#define SM_PRE   (SM_DYN + 65536 + 13056)   // [2][16][66] f32 = 8448B
#define SM_SIZE  (SM_DYN + 65536 + 13056 + 8448)

__device__ __forceinline__ float wred(float v) {
#pragma unroll
  for (int m = 32; m >= 1; m >>= 1) v += __shfl_xor(v, m);
  return v;
}
__device__ __forceinline__ float wmax64(float v) {
#pragma unroll
  for (int m = 32; m >= 1; m >>= 1) v = fmaxf(v, __shfl_xor(v, m));
  return v;
}
__device__ __forceinline__ float lane_bcast(float v, int r) {
  return __builtin_bit_cast(float, __builtin_amdgcn_readlane(__builtin_bit_cast(int, v), r));
}

// ---- LLC-coherent (sc0 sc1) access helpers: bypass L1 and non-coherent XCD L2 ----
__device__ __forceinline__ void st_llc32(void* p, unsigned v) {
  asm volatile("global_store_dword %0, %1, off sc0 sc1" :: "v"(p), "v"(v) : "memory");
}
__device__ __forceinline__ void st_llc16b(void* p, unsigned short v) {
  unsigned vv = v;
  asm volatile("global_store_short %0, %1, off sc0 sc1" :: "v"(p), "v"(vv) : "memory");
}
__device__ __forceinline__ unsigned ld_llc32(const void* p) {
  unsigned r;
  asm volatile("global_load_dword %0, %1, off sc0 sc1\n\ts_waitcnt vmcnt(0)"
               : "=v"(r) : "v"(p) : "memory");
  return r;
}
__device__ __forceinline__ void ld_llc_4x8(const void* p, u64& a, u64& b, u64& c, u64& d) {
  asm volatile(
      "global_load_dwordx2 %0, %4, off sc0 sc1\n\t"
      "global_load_dwordx2 %1, %4, off offset:8 sc0 sc1\n\t"
      "global_load_dwordx2 %2, %4, off offset:16 sc0 sc1\n\t"
      "global_load_dwordx2 %3, %4, off offset:24 sc0 sc1\n\t"
      "s_waitcnt vmcnt(0)"
      : "=&v"(a), "=&v"(b), "=&v"(c), "=&v"(d) : "v"(p) : "memory");
}
__device__ __forceinline__ u32x4v ld_llc_16(const void* p) {
  u32x4v r;
  asm volatile("global_load_dwordx4 %0, %1, off sc0 sc1\n\ts_waitcnt vmcnt(0)"
               : "=v"(r) : "v"(p) : "memory");
  return r;
}

// Fence-free group barrier. Ordering argument:
//  producer: sc0sc1 stores -> explicit vmcnt(0) drain (stores complete AT LLC)
//            -> __syncthreads -> tid0 relaxed agent atomic add (RMW at LLC,
//            issued strictly after drain).
//  consumer: tid0 spins on sc0sc1 load of ctr (reads LLC) -> __syncthreads ->
//            data loads are sc0sc1 (read LLC directly; no stale L1/L2 possible).
// No fences -> XCD L2 contents (weights, R) stay valid and warm.
__device__ __forceinline__ void group_barrier(unsigned* ctr, int tid, unsigned target) {
  asm volatile("s_waitcnt vmcnt(0)" ::: "memory");
  __syncthreads();
  if (tid == 0) {
    __hip_atomic_fetch_add(ctr, 1u, __ATOMIC_RELAXED, __HIP_MEMORY_SCOPE_AGENT);
    while (ld_llc32(ctr) < target) __builtin_amdgcn_s_sleep(2);
  }
  __syncthreads();
}

// transpose + f32->bf16: dst[j][i] = src[i][j], 1024x1024; z selects matrix
__global__ __launch_bounds__(256) void transcvt(const float* __restrict__ w1,
                                                const float* __restrict__ w2,
                                                const float* __restrict__ wr,
                                                bf16_t* __restrict__ out) {
  __shared__ float tl[64][65];
  const float* src = (blockIdx.z == 0) ? w1 : (blockIdx.z == 1) ? w2 : wr;
  bf16_t* dst = out + (size_t)blockIdx.z * (1u << 20);
  const int i0 = blockIdx.x * 64, j0 = blockIdx.y * 64;
  const int t = threadIdx.x;
#pragma unroll
  for (int it = 0; it < 4; ++it) {
    int r = (t >> 4) + it * 16;
    int c4 = (t & 15) * 4;
    const float4 v = *reinterpret_cast<const float4*>(&src[(size_t)(i0 + r) * 1024 + j0 + c4]);
    tl[r][c4] = v.x; tl[r][c4 + 1] = v.y; tl[r][c4 + 2] = v.z; tl[r][c4 + 3] = v.w;
  }
  __syncthreads();
  const int orow = t >> 2, seg = t & 3;
  bf16x8 v0, v1;
#pragma unroll
  for (int u = 0; u < 8; ++u) {
    v0[u] = (bf16_t)tl[seg * 16 + u][orow];
    v1[u] = (bf16_t)tl[seg * 16 + 8 + u][orow];
  }
  bf16_t* dp = dst + (size_t)(j0 + orow) * 1024 + i0 + seg * 16;
  *reinterpret_cast<bf16x8*>(dp) = v0;
  *reinterpret_cast<bf16x8*>(dp + 8) = v1;
}

__global__ __launch_bounds__(1024) void interp2(
    const float* __restrict__ opcode_probs, const float* __restrict__ k_write,
    const float* __restrict__ q_read, const float* __restrict__ gate,
    const float* __restrict__ ln1_g, const float* __restrict__ ln1_b, const float* __restrict__ b1,
    const float* __restrict__ ln2_g, const float* __restrict__ ln2_b, const float* __restrict__ b2,
    const float* __restrict__ b_res, const float* __restrict__ lno_g, const float* __restrict__ lno_b,
    char* __restrict__ ws, float* __restrict__ R) {
  __shared__ __align__(16) char smem[SM_SIZE];
  float* wvp  = (float*)(smem + SM_WV);
  float* at0p = (float*)(smem + SM_AT0P);
  float* at1p = (float*)(smem + SM_AT1P);
  float* sc0p = (float*)(smem + SM_SC0);
  float* sc1p = (float*)(smem + SM_SC1);
  float* scwp = (float*)(smem + SM_SCW);
  float* redp = (float*)(smem + SM_RED);
  float* pbp  = (float*)(smem + SM_PB);
  float* q0p  = (float*)(smem + SM_Q0);
  float* q1p  = (float*)(smem + SM_Q1);
  float* kwp  = (float*)(smem + SM_KW);

  const int b = blockIdx.x;
  const int g = b >> 4, m = b & 15;       // group g: consecutive blocks 16g..16g+15
  const int q = b;                        // batch owned for per-batch phases
  const int tid = threadIdx.x;
  const int w = tid >> 6, lane = tid & 63;
  const int ln15 = lane & 15, kgrp = lane >> 4;

  const bf16_t* w1t = (const bf16_t*)(ws + WS_W1T);
  const bf16_t* w2t = (const bf16_t*)(ws + WS_W2T);
  const bf16_t* wrt = (const bf16_t*)(ws + WS_WRT);
  unsigned* xnp   = (unsigned*)(ws + WS_XNP);   // packed (bf16 xn0 | bf16 xn1)
  bf16_t*  mixp   = (bf16_t*)(ws + WS_MIXP);
  unsigned* gtw   = (unsigned*)(ws + WS_GT);    // f32 bits
  unsigned* ctr   = (unsigned*)(ws + WS_CTR) + g * 16;

  float* Rb = R + (size_t)q * (NREG * DD);
  unsigned nbar = 0;

  for (int t = 0; t < LINES; ++t) {
    // ---- Phase A: stage q0,q1,kw; attention scores ----
    const float* qb = q_read + ((size_t)q * LINES + t) * (2 * DD);
    const float* kb = k_write + ((size_t)q * LINES + t) * DD;
    q0p[tid] = qb[tid];
    q1p[tid] = qb[DD + tid];
    kwp[tid] = kb[tid];
    if (tid == 0) pbp[0] = gate[(size_t)q * LINES + t];
    __syncthreads();
#pragma unroll
    for (int rr = 0; rr < 4; ++rr) {
      int r = w * 4 + rr;
      const float* Rr = Rb + (size_t)r * DD;
      float a0 = 0.f, a1 = 0.f, aw = 0.f;
#pragma unroll
      for (int j = 0; j < 16; ++j) {
        int d = j * 64 + lane;
        float rv = Rr[d];
        a0 = fmaf(rv, q0p[d], a0);
        a1 = fmaf(rv, q1p[d], a1);
        aw = fmaf(rv, kwp[d], aw);
      }
      a0 = wred(a0); a1 = wred(a1); aw = wred(aw);
      if (lane == 0) { sc0p[r] = a0 * SCALE; sc1p[r] = a1 * SCALE; scwp[r] = aw * SCALE; }
    }
    __syncthreads();
    // ---- Phase B: three 64-wide softmaxes ----
    if (w < 3) {
      const float* src = (w == 0) ? sc0p : (w == 1) ? sc1p : scwp;
      float* dst = (w == 0) ? at0p : (w == 1) ? at1p : wvp;
      float v = src[lane];
      float mx = wmax64(v);
      float e = expf(v - mx);
      float s = wred(e);
      dst[lane] = e / s;
    }
    __syncthreads();
    // ---- Phase C: op_s (thread owns d=tid) ----
    float a0r = at0p[lane], a1r = at1p[lane];
    float os0 = 0.f, os1 = 0.f;
#pragma unroll 8
    for (int r = 0; r < NREG; ++r) {
      float rv = Rb[(size_t)r * DD + tid];
      os0 = fmaf(lane_bcast(a0r, r), rv, os0);
      os1 = fmaf(lane_bcast(a1r, r), rv, os1);
    }
    // ---- Phase D: LN1/LN2 -> xnp (packed bf16 pair, LLC store) ----
    {
      float s0 = wred(os0), qq0 = wred(os0 * os0);
      float s1 = wred(os1), qq1 = wred(os1 * os1);
      if (lane == 0) { redp[w*4] = s0; redp[w*4+1] = qq0; redp[w*4+2] = s1; redp[w*4+3] = qq1; }
      __syncthreads();
      float S0 = 0, Q0 = 0, S1 = 0, Q1 = 0;
#pragma unroll
      for (int i = 0; i < 16; ++i) { S0 += redp[i*4]; Q0 += redp[i*4+1]; S1 += redp[i*4+2]; Q1 += redp[i*4+3]; }
      float m0 = S0 * (1.f / DD), v0 = fmaxf(Q0 * (1.f / DD) - m0 * m0, 0.f);
      float m1 = S1 * (1.f / DD), v1 = fmaxf(Q1 * (1.f / DD) - m1 * m1, 0.f);
      float xn0v = (os0 - m0) * rsqrtf(v0 + EPS) * ln1_g[tid] + ln1_b[tid];
      float xn1v = (os1 - m1) * rsqrtf(v1 + EPS) * ln2_g[tid] + ln2_b[tid];
      unsigned pw = (unsigned)__builtin_bit_cast(unsigned short, (bf16_t)xn0v)
                  | ((unsigned)__builtin_bit_cast(unsigned short, (bf16_t)xn1v) << 16);
      st_llc32(&xnp[((size_t)g * 16 + m) * DD + tid], pw);
    }
    group_barrier(ctr, tid, 16u * (++nbar));   // bar_A: xnp ready

    // ---- Stage BOTH A-tiles (xn0 -> AT0, xn1 -> AT1), XOR-swizzled ----
    {
      const char* base = (const char*)(xnp + (size_t)g * (16 * DD));
#pragma unroll
      for (int c = 0; c < 2; ++c) {
        int ch = tid + c * 1024;
        int row = ch >> 7, k16 = ch & 127;
        u64 w0, w1v, w2v, w3v;
        ld_llc_4x8(base + (size_t)row * 4096 + k16 * 32, w0, w1v, w2v, w3v);
        us16x8 v0, v1;
        v0[0] = (unsigned short)w0;          v1[0] = (unsigned short)(w0 >> 16);
        v0[1] = (unsigned short)(w0 >> 32);  v1[1] = (unsigned short)(w0 >> 48);
        v0[2] = (unsigned short)w1v;         v1[2] = (unsigned short)(w1v >> 16);
        v0[3] = (unsigned short)(w1v >> 32); v1[3] = (unsigned short)(w1v >> 48);
        v0[4] = (unsigned short)w2v;         v1[4] = (unsigned short)(w2v >> 16);
        v0[5] = (unsigned short)(w2v >> 32); v1[5] = (unsigned short)(w2v >> 48);
        v0[6] = (unsigned short)w3v;         v1[6] = (unsigned short)(w3v >> 16);
        v0[7] = (unsigned short)(w3v >> 32); v1[7] = (unsigned short)(w3v >> 48);
        unsigned byte = (unsigned)(row * 2048 + k16 * 16) ^ ((unsigned)(row & 7) << 4);
        *(us16x8*)(smem + SM_AT0 + byte) = v0;
        *(us16x8*)(smem + SM_AT1 + byte) = v1;
      }
    }
    __syncthreads();

    // ---- Phase E: two 16x1024 @ 1024x64 MFMA GEMMs (f-slice of this block) ----
#pragma unroll
    for (int gm = 0; gm < 2; ++gm) {
      const char* atile = smem + (gm ? SM_AT1 : SM_AT0);
      const int ns = w & 3, ks = w >> 2;          // 4 n-subtiles x 4 k-splits
      const bf16_t* bsrc = (gm ? w2t : w1t) + (size_t)(64 * m + ns * 16 + ln15) * DD;
      f32x4 acc = {0.f, 0.f, 0.f, 0.f};
#pragma unroll
      for (int kc = 0; kc < 8; ++kc) {
        int kb = ks * 256 + kc * 32 + kgrp * 8;
        unsigned abyte = ((unsigned)(ln15 * 2048 + kb * 2)) ^ ((unsigned)(ln15 & 7) << 4);
        bf16x8 av = *(const bf16x8*)(atile + abyte);
        bf16x8 bv = *(const bf16x8*)(bsrc + kb);
        acc = __builtin_amdgcn_mfma_f32_16x16x32_bf16(av, bv, acc, 0, 0, 0);
      }
      __syncthreads();
      float* red2 = (float*)(smem + SM_RED2);
      if (ks > 0) {
#pragma unroll
        for (int r2 = 0; r2 < 4; ++r2)
          red2[((ks - 1) * 4 + ns) * (16 * 17) + (kgrp * 4 + r2) * 17 + ln15] = acc[r2];
      }
      __syncthreads();
      if (ks == 0) {
        float* prep = (float*)(smem + SM_PRE) + gm * (16 * 66);
#pragma unroll
        for (int r2 = 0; r2 < 4; ++r2) {
          int crow = kgrp * 4 + r2;
          float v = acc[r2];
#pragma unroll
          for (int kk = 0; kk < 3; ++kk)
            v += red2[(kk * 4 + ns) * (16 * 17) + crow * 17 + ln15];
          prep[crow * 66 + ns * 16 + ln15] = v;
        }
      }
      __syncthreads();
    }
    // ---- Phase F: per-16 softmax + modular digit conv; wave w = batch-row w ----
    {
      float* prep = (float*)(smem + SM_PRE);
      const int bb2 = w, c = lane;
      float xp = prep[bb2 * 66 + c] + b1[64 * m + c];
      float yp = prep[16 * 66 + bb2 * 66 + c] + b2[64 * m + c];
      float mx1 = xp, mx2 = yp;
#pragma unroll
      for (int msk = 1; msk < 16; msk <<= 1) {
        mx1 = fmaxf(mx1, __shfl_xor(mx1, msk));
        mx2 = fmaxf(mx2, __shfl_xor(mx2, msk));
      }
      float e1 = expf(xp - mx1), e2 = expf(yp - mx2);
      float s1 = e1, s2 = e2;
#pragma unroll
      for (int msk = 1; msk < 16; msk <<= 1) {
        s1 += __shfl_xor(s1, msk);
        s2 += __shfl_xor(s2, msk);
      }
      float x = e1 / s1, y = e2 / s2;
      int mm = lane & 15, basel = lane & ~15;
      float addv = 0.f, subv = 0.f;
#pragma unroll
      for (int i = 0; i < 16; ++i) {
        float xi = __shfl(x, basel + i);
        float ya = __shfl(y, basel + ((mm - i) & 15));
        float ys = __shfl(y, basel + ((i - mm) & 15));
        addv = fmaf(xi, ya, addv);
        subv = fmaf(xi, ys, subv);
      }
      int q2 = g * 16 + bb2;
      const float* pr = opcode_probs + ((size_t)q2 * LINES + t) * 2;
      float mix = pr[0] * addv + pr[1] * subv;
      st_llc16b(&mixp[((size_t)g * 16 + bb2) * DD + 64 * m + c],
                __builtin_bit_cast(unsigned short, (bf16_t)mix));
    }
    group_barrier(ctr, tid, 16u * (++nbar));   // bar_B: mixp ready

    // ---- Phase G: mix(16x1024) @ w_res(1024x1024), d-slice of this block ----
    {
      const char* base = (const char*)(mixp + (size_t)g * (16 * DD));
#pragma unroll
      for (int c = 0; c < 2; ++c) {
        int ch = tid + c * 1024;
        int row = ch >> 7, k16 = ch & 127;
        u32x4v v = ld_llc_16(base + (size_t)row * 2048 + k16 * 16);
        unsigned byte = (unsigned)(row * 2048 + k16 * 16) ^ ((unsigned)(row & 7) << 4);
        *(u32x4v*)(smem + SM_AT0 + byte) = v;
      }
      __syncthreads();
      const int ns = w & 3, ks = w >> 2;
      const bf16_t* bsrc = wrt + (size_t)(64 * m + ns * 16 + ln15) * DD;
      f32x4 acc = {0.f, 0.f, 0.f, 0.f};
#pragma unroll
      for (int kc = 0; kc < 8; ++kc) {
        int kb = ks * 256 + kc * 32 + kgrp * 8;
        unsigned abyte = ((unsigned)(ln15 * 2048 + kb * 2)) ^ ((unsigned)(ln15 & 7) << 4);
        bf16x8 av = *(const bf16x8*)(smem + SM_AT0 + abyte);
        bf16x8 bv = *(const bf16x8*)(bsrc + kb);
        acc = __builtin_amdgcn_mfma_f32_16x16x32_bf16(av, bv, acc, 0, 0, 0);
      }
      __syncthreads();
      float* red2 = (float*)(smem + SM_RED2);
      if (ks > 0) {
#pragma unroll
        for (int r2 = 0; r2 < 4; ++r2)
          red2[((ks - 1) * 4 + ns) * (16 * 17) + (kgrp * 4 + r2) * 17 + ln15] = acc[r2];
      }
      __syncthreads();
      if (ks == 0) {
        int f = 64 * m + ns * 16 + ln15;
#pragma unroll
        for (int r2 = 0; r2 < 4; ++r2) {
          int crow = kgrp * 4 + r2;
          float v = acc[r2];
#pragma unroll
          for (int kk = 0; kk < 3; ++kk)
            v += red2[(kk * 4 + ns) * (16 * 17) + crow * 17 + ln15];
          st_llc32(&gtw[((size_t)g * 16 + crow) * DD + f],
                   __builtin_bit_cast(unsigned, v + b_res[f]));
        }
      }
    }
    group_barrier(ctr, tid, 16u * (++nbar));   // bar_C: gt ready

    // ---- Phase H: output LN (thread owns d=tid, own batch row) ----
    float vv;
    {
      float xv = __builtin_bit_cast(float, ld_llc32(&gtw[((size_t)g * 16 + m) * DD + tid]));
      float s1 = wred(xv), s2 = wred(xv * xv);
      if (lane == 0) { redp[w * 2] = s1; redp[w * 2 + 1] = s2; }
      __syncthreads();
      float S = 0.f, Q = 0.f;
#pragma unroll
      for (int i = 0; i < 16; ++i) { S += redp[i * 2]; Q += redp[i * 2 + 1]; }
      float mn = S * (1.f / DD), vr = fmaxf(Q * (1.f / DD) - mn * mn, 0.f);
      vv = (xv - mn) * rsqrtf(vr + EPS) * lno_g[tid] + lno_b[tid];
    }
    // ---- Phase I: gated write-back (block-local R, plain cached) ----
    {
      float wvreg = wvp[lane];
      float gtv = pbp[0];
#pragma unroll 4
      for (int r = 0; r < NREG; ++r) {
        float gg = gtv * lane_bcast(wvreg, r);
        size_t idx = (size_t)r * DD + tid;
        Rb[idx] = Rb[idx] * (1.f - gg) + gg * vv;
      }
    }
    __syncthreads();
  }
}

// ---------------- fallback (round-1 structure, f32 weights) ----------------
__global__ __launch_bounds__(1024) void interp_fb(
    const float* __restrict__ opcode_probs, const float* __restrict__ k_write,
    const float* __restrict__ q_read, const float* __restrict__ gate,
    const float* __restrict__ ln1_g, const float* __restrict__ ln1_b,
    const float* __restrict__ w1, const float* __restrict__ b1,
    const float* __restrict__ ln2_g, const float* __restrict__ ln2_b,
    const float* __restrict__ w2, const float* __restrict__ b2,
    const float* __restrict__ w_res, const float* __restrict__ b_res,
    const float* __restrict__ lno_g, const float* __restrict__ lno_b,
    float* __restrict__ R) {
  __shared__ float q0s[DD], q1s[DD], kws[DD];
  __shared__ float sc0[NREG], sc1[NREG], scw[NREG];
  __shared__ float at0[NREG], at1[NREG], wv[NREG];
  __shared__ float xn0[DD], xn1[DD];
  __shared__ float mixs[FF];
  __shared__ float val[DD];
  __shared__ float red[64];
  const int b = blockIdx.x;
  const int tid = threadIdx.x;
  const int w = tid >> 6, lane = tid & 63;
  float* Rb = R + (size_t)b * NREG * DD;
  for (int t = 0; t < LINES; ++t) {
    const float* qb = q_read + ((size_t)b * LINES + t) * 2 * DD;
    const float* kb = k_write + ((size_t)b * LINES + t) * DD;
    q0s[tid] = qb[tid]; q1s[tid] = qb[DD + tid]; kws[tid] = kb[tid];
    __syncthreads();
#pragma unroll
    for (int rr = 0; rr < 4; ++rr) {
      int r = w * 4 + rr;
      const float* Rr = Rb + (size_t)r * DD;
      float a0 = 0.f, a1 = 0.f, aw = 0.f;
#pragma unroll
      for (int j = 0; j < 16; ++j) {
        int d = j * 64 + lane;
        float rv = Rr[d];
        a0 += rv * q0s[d]; a1 += rv * q1s[d]; aw += rv * kws[d];
      }
      a0 = wred(a0); a1 = wred(a1); aw = wred(aw);
      if (lane == 0) { sc0[r] = a0 * SCALE; sc1[r] = a1 * SCALE; scw[r] = aw * SCALE; }
    }
    __syncthreads();
    if (w < 3) {
      const float* src = (w == 0) ? sc0 : (w == 1) ? sc1 : scw;
      float* dst = (w == 0) ? at0 : (w == 1) ? at1 : wv;
      float v = src[lane];
      float mx = wmax64(v);
      float e = expf(v - mx);
      float s = wred(e);
      dst[lane] = e / s;
    }
    __syncthreads();
    float os0 = 0.f, os1 = 0.f;
#pragma unroll 4
    for (int r = 0; r < NREG; ++r) {
      float rv = Rb[(size_t)r * DD + tid];
      os0 += at0[r] * rv; os1 += at1[r] * rv;
    }
    {
      float s0 = wred(os0), qq0 = wred(os0 * os0);
      float s1 = wred(os1), qq1 = wred(os1 * os1);
      if (lane == 0) { red[w*4] = s0; red[w*4+1] = qq0; red[w*4+2] = s1; red[w*4+3] = qq1; }
      __syncthreads();
      float S0 = 0, Q0 = 0, S1 = 0, Q1 = 0;
#pragma unroll
      for (int i = 0; i < 16; ++i) { S0 += red[i*4]; Q0 += red[i*4+1]; S1 += red[i*4+2]; Q1 += red[i*4+3]; }
      float m0 = S0 / DD, v0 = fmaxf(Q0 / DD - m0 * m0, 0.f);
      float m1 = S1 / DD, v1 = fmaxf(Q1 / DD - m1 * m1, 0.f);
      xn0[tid] = (os0 - m0) * rsqrtf(v0 + EPS) * ln1_g[tid] + ln1_b[tid];
      xn1[tid] = (os1 - m1) * rsqrtf(v1 + EPS) * ln2_g[tid] + ln2_b[tid];
      __syncthreads();
    }
    float p1v = b1[tid], p2v = b2[tid];
    {
      const float* c1 = w1 + tid;
      const float* c2 = w2 + tid;
#pragma unroll 4
      for (int d = 0; d < DD; ++d) {
        p1v += xn0[d] * c1[(size_t)d * FF];
        p2v += xn1[d] * c2[(size_t)d * FF];
      }
    }
    {
      int mmm = lane & 15, basel = lane & ~15;
      float mx1 = p1v, mx2 = p2v;
      for (int msk = 1; msk < 16; msk <<= 1) {
        mx1 = fmaxf(mx1, __shfl_xor(mx1, msk));
        mx2 = fmaxf(mx2, __shfl_xor(mx2, msk));
      }
      float e1 = expf(p1v - mx1), e2 = expf(p2v - mx2);
      float s1 = e1, s2 = e2;
      for (int msk = 1; msk < 16; msk <<= 1) { s1 += __shfl_xor(s1, msk); s2 += __shfl_xor(s2, msk); }
      float x = e1 / s1, y = e2 / s2;
      float addv = 0.f, subv = 0.f;
#pragma unroll
      for (int i = 0; i < 16; ++i) {
        float xi = __shfl(x, basel + i);
        float ya = __shfl(y, basel + ((mmm - i) & 15));
        float ys = __shfl(y, basel + ((i - mmm) & 15));
        addv += xi * ya; subv += xi * ys;
      }
      const float* pr = opcode_probs + ((size_t)b * LINES + t) * 2;
      mixs[tid] = pr[0] * addv + pr[1] * subv;
    }
    __syncthreads();
    float acc = b_res[tid];
    {
      const float* cr = w_res + tid;
#pragma unroll 4
      for (int f = 0; f < FF; ++f) acc += mixs[f] * cr[(size_t)f * DD];
    }
    {
      float s1 = wred(acc), s2 = wred(acc * acc);
      if (lane == 0) { red[w*2] = s1; red[w*2+1] = s2; }
      __syncthreads();
      float S = 0, Q = 0;
#pragma unroll
      for (int i = 0; i < 16; ++i) { S += red[i*2]; Q += red[i*2+1]; }
      float mn = S / DD, vr = fmaxf(Q / DD - mn * mn, 0.f);
      val[tid] = (acc - mn) * rsqrtf(vr + EPS) * lno_g[tid] + lno_b[tid];
      __syncthreads();
    }
    {
      float gt_ = gate[(size_t)b * LINES + t];
      float vv = val[tid];
#pragma unroll 4
      for (int r = 0; r < NREG; ++r) {
        float gg = gt_ * wv[r];
        size_t idx = (size_t)r * DD + tid;
        Rb[idx] = Rb[idx] * (1.f - gg) + gg * vv;
      }
    }
    __syncthreads();
  }
}

extern "C" void kernel_launch(void* const* d_in, const int* in_sizes, int n_in,
                              void* d_out, int out_size, void* d_ws, size_t ws_size,
                              hipStream_t stream) {
  const float* opcode = (const float*)d_in[0];
  const float* registers = (const float*)d_in[1];
  const float* k_write = (const float*)d_in[2];
  const float* q_read = (const float*)d_in[3];
  const float* gate = (const float*)d_in[5];
  const float* ln1_g = (const float*)d_in[6];
  const float* ln1_b = (const float*)d_in[7];
  const float* w1 = (const float*)d_in[8];
  const float* b1 = (const float*)d_in[9];
  const float* ln2_g = (const float*)d_in[10];
  const float* ln2_b = (const float*)d_in[11];
  const float* w2 = (const float*)d_in[12];
  const float* b2 = (const float*)d_in[13];
  const float* w_res = (const float*)d_in[14];
  const float* b_res = (const float*)d_in[15];
  const float* lno_g = (const float*)d_in[16];
  const float* lno_b = (const float*)d_in[17];
  float* R = (float*)d_out;

  hipMemcpyAsync(R, registers, (size_t)BB * NREG * DD * sizeof(float),
                 hipMemcpyDeviceToDevice, stream);

  if (ws_size >= (size_t)WS_NEED) {
    transcvt<<<dim3(16, 16, 3), 256, 0, stream>>>(w1, w2, w_res, (bf16_t*)d_ws);
    hipMemsetAsync((char*)d_ws + WS_CTR, 0, 1024, stream);
    interp2<<<BB, 1024, 0, stream>>>(opcode, k_write, q_read, gate, ln1_g, ln1_b, b1,
                                     ln2_g, ln2_b, b2, b_res, lno_g, lno_b,
                                     (char*)d_ws, R);
  } else {
    interp_fb<<<BB, 1024, 0, stream>>>(opcode, k_write, q_read, gate, ln1_g, ln1_b,
                                       w1, b1, ln2_g, ln2_b, w2, b2, w_res, b_res,
                                       lno_g, lno_b, R);
  }
}

// Round 5
// 4138.235 us; speedup vs baseline: 3.1826x; 1.5620x over previous
//
#include <hip/hip_runtime.h>
#include <hip/hip_bf16.h>

#define BB 256
#define LINES 64
#define NREG 64
#define DD 1024
#define FF 1024

constexpr float EPS = 1e-5f;
constexpr float SCALE = 0.03125f; // 1/sqrt(1024)

typedef __bf16 bf16_t;
typedef bf16_t bf16x8 __attribute__((ext_vector_type(8)));
typedef unsigned short us16x8 __attribute__((ext_vector_type(8)));
typedef float f32x4 __attribute__((ext_vector_type(4)));
typedef unsigned u32x4v __attribute__((ext_vector_type(4)));
typedef unsigned long long u64;

// ---------------- d_ws layout (bytes) ----------------
#define WS_W1T   0u                         // w1^T  [f][d] bf16, 2MB
#define WS_W2T   (2u << 20)                 // w2^T  [f][d] bf16, 2MB
#define WS_WRT   (4u << 20)                 // w_res^T [d][f] bf16, 2MB
#define WS_XNP   (6u << 20)                 // xnp [16g][16m][1024] u32 (bf16 xn0|xn1), 1MB
#define WS_MIXP  (7u << 20)                 // mixp [16g][16][1024] bf16, 512KB
#define WS_GT    ((7u << 20) + (1u << 19))  // gt  [16g][16][1024] f32, 1MB
#define WS_CTR   ((8u << 20) + (1u << 19))  // 16 counters x 64B
#define WS_NEED  (WS_CTR + 1024u)

// ---------------- LDS layout (bytes) ----------------
#define SM_WV    0
#define SM_AT0P  256
#define SM_AT1P  512
#define SM_SC0   768
#define SM_SC1   1024
#define SM_SCW   1280
#define SM_RED   1536
#define SM_DYN   2048
#define SM_OSB   SM_DYN                     // [16][1088] f32 = 69632B (aliases AT0/AT1/RED2 head; disjoint in time)
#define SM_AT0   SM_DYN                     // 32KB bf16 [16][1024] XOR-swizzled (xn0 / mix tile)
#define SM_AT1   (SM_DYN + 32768)           // 32KB tile for xn1
#define SM_RED2  (SM_DYN + 65536)           // [3][4][16][17] f32 = 13056B
#define SM_PRE   (SM_DYN + 65536 + 13056)   // [2][16][66] f32 = 8448B
#define SM_VAL   (SM_DYN + 65536 + 13056 + 8448)  // [1088] f32 padded = 4352B
#define SM_SIZE  (SM_VAL + 4352)

__device__ __forceinline__ float wred(float v) {
#pragma unroll
  for (int m = 32; m >= 1; m >>= 1) v += __shfl_xor(v, m);
  return v;
}
__device__ __forceinline__ float wmax64(float v) {
#pragma unroll
  for (int m = 32; m >= 1; m >>= 1) v = fmaxf(v, __shfl_xor(v, m));
  return v;
}

// ---- LLC-coherent (sc0 sc1) access helpers: bypass L1 and non-coherent XCD L2 ----
__device__ __forceinline__ void st_llc32(void* p, unsigned v) {
  asm volatile("global_store_dword %0, %1, off sc0 sc1" :: "v"(p), "v"(v) : "memory");
}
__device__ __forceinline__ void st_llc16b(void* p, unsigned short v) {
  unsigned vv = v;
  asm volatile("global_store_short %0, %1, off sc0 sc1" :: "v"(p), "v"(vv) : "memory");
}
__device__ __forceinline__ unsigned ld_llc32(const void* p) {
  unsigned r;
  asm volatile("global_load_dword %0, %1, off sc0 sc1\n\ts_waitcnt vmcnt(0)"
               : "=v"(r) : "v"(p) : "memory");
  return r;
}
__device__ __forceinline__ void ld_llc_4x8(const void* p, u64& a, u64& b, u64& c, u64& d) {
  asm volatile(
      "global_load_dwordx2 %0, %4, off sc0 sc1\n\t"
      "global_load_dwordx2 %1, %4, off offset:8 sc0 sc1\n\t"
      "global_load_dwordx2 %2, %4, off offset:16 sc0 sc1\n\t"
      "global_load_dwordx2 %3, %4, off offset:24 sc0 sc1\n\t"
      "s_waitcnt vmcnt(0)"
      : "=&v"(a), "=&v"(b), "=&v"(c), "=&v"(d) : "v"(p) : "memory");
}
__device__ __forceinline__ u32x4v ld_llc_16(const void* p) {
  u32x4v r;
  asm volatile("global_load_dwordx4 %0, %1, off sc0 sc1\n\ts_waitcnt vmcnt(0)"
               : "=v"(r) : "v"(p) : "memory");
  return r;
}

// Fence-free group barrier (validated round 4): producer drains vmcnt ->
// syncthreads -> tid0 relaxed agent atomic (RMW at LLC); consumer spins on
// sc0sc1 load; data moves exclusively via sc0sc1 accesses. No cache flushes.
__device__ __forceinline__ void group_barrier(unsigned* ctr, int tid, unsigned target) {
  asm volatile("s_waitcnt vmcnt(0)" ::: "memory");
  __syncthreads();
  if (tid == 0) {
    __hip_atomic_fetch_add(ctr, 1u, __ATOMIC_RELAXED, __HIP_MEMORY_SCOPE_AGENT);
    while (ld_llc32(ctr) < target) __builtin_amdgcn_s_sleep(2);
  }
  __syncthreads();
}

// transpose + f32->bf16: dst[j][i] = src[i][j], 1024x1024; z selects matrix
__global__ __launch_bounds__(256) void transcvt(const float* __restrict__ w1,
                                                const float* __restrict__ w2,
                                                const float* __restrict__ wr,
                                                bf16_t* __restrict__ out) {
  __shared__ float tl[64][65];
  const float* src = (blockIdx.z == 0) ? w1 : (blockIdx.z == 1) ? w2 : wr;
  bf16_t* dst = out + (size_t)blockIdx.z * (1u << 20);
  const int i0 = blockIdx.x * 64, j0 = blockIdx.y * 64;
  const int t = threadIdx.x;
#pragma unroll
  for (int it = 0; it < 4; ++it) {
    int r = (t >> 4) + it * 16;
    int c4 = (t & 15) * 4;
    const float4 v = *reinterpret_cast<const float4*>(&src[(size_t)(i0 + r) * 1024 + j0 + c4]);
    tl[r][c4] = v.x; tl[r][c4 + 1] = v.y; tl[r][c4 + 2] = v.z; tl[r][c4 + 3] = v.w;
  }
  __syncthreads();
  const int orow = t >> 2, seg = t & 3;
  bf16x8 v0, v1;
#pragma unroll
  for (int u = 0; u < 8; ++u) {
    v0[u] = (bf16_t)tl[seg * 16 + u][orow];
    v1[u] = (bf16_t)tl[seg * 16 + 8 + u][orow];
  }
  bf16_t* dp = dst + (size_t)(j0 + orow) * 1024 + i0 + seg * 16;
  *reinterpret_cast<bf16x8*>(dp) = v0;
  *reinterpret_cast<bf16x8*>(dp + 8) = v1;
}

__global__ __launch_bounds__(1024, 4) void interp3(
    const float* __restrict__ opcode_probs, const float* __restrict__ Rin,
    const float* __restrict__ k_write, const float* __restrict__ q_read,
    const float* __restrict__ gate,
    const float* __restrict__ ln1_g, const float* __restrict__ ln1_b, const float* __restrict__ b1,
    const float* __restrict__ ln2_g, const float* __restrict__ ln2_b, const float* __restrict__ b2,
    const float* __restrict__ b_res, const float* __restrict__ lno_g, const float* __restrict__ lno_b,
    char* __restrict__ ws, float* __restrict__ Rout) {
  __shared__ __align__(16) char smem[SM_SIZE];
  float* wvp  = (float*)(smem + SM_WV);
  float* at0p = (float*)(smem + SM_AT0P);
  float* at1p = (float*)(smem + SM_AT1P);
  float* sc0p = (float*)(smem + SM_SC0);
  float* sc1p = (float*)(smem + SM_SC1);
  float* scwp = (float*)(smem + SM_SCW);
  float* redp = (float*)(smem + SM_RED);

  const int b = blockIdx.x;
  const int g = b >> 4, m = b & 15;       // group g: consecutive blocks 16g..16g+15
  const int bq = b;                       // batch owned for per-batch phases
  const int tid = threadIdx.x;
  const int w = tid >> 6, lane = tid & 63;
  const int ln15 = lane & 15, kgrp = lane >> 4;

  const bf16_t* w1t = (const bf16_t*)(ws + WS_W1T);
  const bf16_t* w2t = (const bf16_t*)(ws + WS_W2T);
  const bf16_t* wrt = (const bf16_t*)(ws + WS_WRT);
  unsigned* xnp   = (unsigned*)(ws + WS_XNP);   // packed (bf16 xn0 | bf16 xn1)
  bf16_t*  mixp   = (bf16_t*)(ws + WS_MIXP);
  unsigned* gtw   = (unsigned*)(ws + WS_GT);    // f32 bits
  unsigned* ctr   = (unsigned*)(ws + WS_CTR) + g * 16;

  // R rows [4w, 4w+4), columns [16*lane, 16*lane+16) live in registers.
  float Rr_[4][16];
  {
    const float* Rsrc = Rin + (size_t)bq * (NREG * DD);
#pragma unroll
    for (int rr = 0; rr < 4; ++rr) {
#pragma unroll
      for (int c = 0; c < 4; ++c) {
        float4 v = *(const float4*)(Rsrc + (size_t)(4 * w + rr) * DD + lane * 16 + c * 4);
        Rr_[rr][c * 4 + 0] = v.x; Rr_[rr][c * 4 + 1] = v.y;
        Rr_[rr][c * 4 + 2] = v.z; Rr_[rr][c * 4 + 3] = v.w;
      }
    }
  }

  unsigned nbar = 0;

  for (int t = 0; t < LINES; ++t) {
    // ---- Phase A: attention scores from register-resident R ----
    {
      const float* qb = q_read + ((size_t)bq * LINES + t) * (2 * DD);
      const float* kb = k_write + ((size_t)bq * LINES + t) * DD;
      const int dbase = lane * 16;
#pragma unroll
      for (int v = 0; v < 3; ++v) {
        const float* src = (v == 0) ? qb : (v == 1) ? (qb + DD) : kb;
        float* dst = (v == 0) ? sc0p : (v == 1) ? sc1p : scwp;
        float qv[16];
#pragma unroll
        for (int c = 0; c < 4; ++c) {
          float4 t4 = *(const float4*)(src + dbase + c * 4);
          qv[c * 4 + 0] = t4.x; qv[c * 4 + 1] = t4.y;
          qv[c * 4 + 2] = t4.z; qv[c * 4 + 3] = t4.w;
        }
#pragma unroll
        for (int rr = 0; rr < 4; ++rr) {
          float s = 0.f;
#pragma unroll
          for (int j = 0; j < 16; ++j) s = fmaf(Rr_[rr][j], qv[j], s);
          s = wred(s);
          if (lane == 0) dst[4 * w + rr] = s * SCALE;
        }
      }
    }
    __syncthreads();
    // ---- Phase B: three 64-wide softmaxes ----
    if (w < 3) {
      const float* src = (w == 0) ? sc0p : (w == 1) ? sc1p : scwp;
      float* dst = (w == 0) ? at0p : (w == 1) ? at1p : wvp;
      float v = src[lane];
      float mx = wmax64(v);
      float e = expf(v - mx);
      float s = wred(e);
      dst[lane] = e / s;
    }
    __syncthreads();
    // ---- Phase C: op_s via register FMAs + padded-LDS cross-wave reduce ----
    float os0, os1;
    {
      float p0[16], p1[16];
#pragma unroll
      for (int j = 0; j < 16; ++j) { p0[j] = 0.f; p1[j] = 0.f; }
#pragma unroll
      for (int rr = 0; rr < 4; ++rr) {
        float a0 = at0p[4 * w + rr], a1 = at1p[4 * w + rr];
#pragma unroll
        for (int j = 0; j < 16; ++j) {
          p0[j] = fmaf(a0, Rr_[rr][j], p0[j]);
          p1[j] = fmaf(a1, Rr_[rr][j], p1[j]);
        }
      }
      float* osb = (float*)(smem + SM_OSB);
      const int rp = (tid >> 4) * 17 + (tid & 15);
#pragma unroll
      for (int j = 0; j < 16; ++j) osb[w * 1088 + lane * 17 + j] = p0[j];
      __syncthreads();
      os0 = 0.f;
#pragma unroll
      for (int ww = 0; ww < 16; ++ww) os0 += osb[ww * 1088 + rp];
      __syncthreads();
#pragma unroll
      for (int j = 0; j < 16; ++j) osb[w * 1088 + lane * 17 + j] = p1[j];
      __syncthreads();
      os1 = 0.f;
#pragma unroll
      for (int ww = 0; ww < 16; ++ww) os1 += osb[ww * 1088 + rp];
    }
    // ---- Phase D: LN1/LN2 -> xnp (packed bf16 pair, LLC store) ----
    {
      float s0 = wred(os0), qq0 = wred(os0 * os0);
      float s1 = wred(os1), qq1 = wred(os1 * os1);
      if (lane == 0) { redp[w*4] = s0; redp[w*4+1] = qq0; redp[w*4+2] = s1; redp[w*4+3] = qq1; }
      __syncthreads();
      float S0 = 0, Q0 = 0, S1 = 0, Q1 = 0;
#pragma unroll
      for (int i = 0; i < 16; ++i) { S0 += redp[i*4]; Q0 += redp[i*4+1]; S1 += redp[i*4+2]; Q1 += redp[i*4+3]; }
      float m0 = S0 * (1.f / DD), v0 = fmaxf(Q0 * (1.f / DD) - m0 * m0, 0.f);
      float m1 = S1 * (1.f / DD), v1 = fmaxf(Q1 * (1.f / DD) - m1 * m1, 0.f);
      float xn0v = (os0 - m0) * rsqrtf(v0 + EPS) * ln1_g[tid] + ln1_b[tid];
      float xn1v = (os1 - m1) * rsqrtf(v1 + EPS) * ln2_g[tid] + ln2_b[tid];
      unsigned pw = (unsigned)__builtin_bit_cast(unsigned short, (bf16_t)xn0v)
                  | ((unsigned)__builtin_bit_cast(unsigned short, (bf16_t)xn1v) << 16);
      st_llc32(&xnp[((size_t)g * 16 + m) * DD + tid], pw);
    }
    group_barrier(ctr, tid, 16u * (++nbar));   // bar_A: xnp ready

    // ---- Stage BOTH A-tiles (xn0 -> AT0, xn1 -> AT1), XOR-swizzled ----
    {
      const char* base = (const char*)(xnp + (size_t)g * (16 * DD));
#pragma unroll
      for (int c = 0; c < 2; ++c) {
        int ch = tid + c * 1024;
        int row = ch >> 7, k16 = ch & 127;
        u64 w0, w1v, w2v, w3v;
        ld_llc_4x8(base + (size_t)row * 4096 + k16 * 32, w0, w1v, w2v, w3v);
        us16x8 v0, v1;
        v0[0] = (unsigned short)w0;          v1[0] = (unsigned short)(w0 >> 16);
        v0[1] = (unsigned short)(w0 >> 32);  v1[1] = (unsigned short)(w0 >> 48);
        v0[2] = (unsigned short)w1v;         v1[2] = (unsigned short)(w1v >> 16);
        v0[3] = (unsigned short)(w1v >> 32); v1[3] = (unsigned short)(w1v >> 48);
        v0[4] = (unsigned short)w2v;         v1[4] = (unsigned short)(w2v >> 16);
        v0[5] = (unsigned short)(w2v >> 32); v1[5] = (unsigned short)(w2v >> 48);
        v0[6] = (unsigned short)w3v;         v1[6] = (unsigned short)(w3v >> 16);
        v0[7] = (unsigned short)(w3v >> 32); v1[7] = (unsigned short)(w3v >> 48);
        unsigned byte = (unsigned)(row * 2048 + k16 * 16) ^ ((unsigned)(row & 7) << 4);
        *(us16x8*)(smem + SM_AT0 + byte) = v0;
        *(us16x8*)(smem + SM_AT1 + byte) = v1;
      }
    }
    __syncthreads();

    // ---- Phase E: two 16x1024 @ 1024x64 MFMA GEMMs (f-slice of this block) ----
#pragma unroll
    for (int gm = 0; gm < 2; ++gm) {
      const char* atile = smem + (gm ? SM_AT1 : SM_AT0);
      const int ns = w & 3, ks = w >> 2;          // 4 n-subtiles x 4 k-splits
      const bf16_t* bsrc = (gm ? w2t : w1t) + (size_t)(64 * m + ns * 16 + ln15) * DD;
      f32x4 acc = {0.f, 0.f, 0.f, 0.f};
#pragma unroll
      for (int kc = 0; kc < 8; ++kc) {
        int kb = ks * 256 + kc * 32 + kgrp * 8;
        unsigned abyte = ((unsigned)(ln15 * 2048 + kb * 2)) ^ ((unsigned)(ln15 & 7) << 4);
        bf16x8 av = *(const bf16x8*)(atile + abyte);
        bf16x8 bv = *(const bf16x8*)(bsrc + kb);
        acc = __builtin_amdgcn_mfma_f32_16x16x32_bf16(av, bv, acc, 0, 0, 0);
      }
      __syncthreads();
      float* red2 = (float*)(smem + SM_RED2);
      if (ks > 0) {
#pragma unroll
        for (int r2 = 0; r2 < 4; ++r2)
          red2[((ks - 1) * 4 + ns) * (16 * 17) + (kgrp * 4 + r2) * 17 + ln15] = acc[r2];
      }
      __syncthreads();
      if (ks == 0) {
        float* prep = (float*)(smem + SM_PRE) + gm * (16 * 66);
#pragma unroll
        for (int r2 = 0; r2 < 4; ++r2) {
          int crow = kgrp * 4 + r2;
          float v = acc[r2];
#pragma unroll
          for (int kk = 0; kk < 3; ++kk)
            v += red2[(kk * 4 + ns) * (16 * 17) + crow * 17 + ln15];
          prep[crow * 66 + ns * 16 + ln15] = v;
        }
      }
      __syncthreads();
    }
    // ---- Phase F: per-16 softmax + modular digit conv; wave w = batch-row w ----
    {
      float* prep = (float*)(smem + SM_PRE);
      const int bb2 = w, c = lane;
      float xp = prep[bb2 * 66 + c] + b1[64 * m + c];
      float yp = prep[16 * 66 + bb2 * 66 + c] + b2[64 * m + c];
      float mx1 = xp, mx2 = yp;
#pragma unroll
      for (int msk = 1; msk < 16; msk <<= 1) {
        mx1 = fmaxf(mx1, __shfl_xor(mx1, msk));
        mx2 = fmaxf(mx2, __shfl_xor(mx2, msk));
      }
      float e1 = expf(xp - mx1), e2 = expf(yp - mx2);
      float s1 = e1, s2 = e2;
#pragma unroll
      for (int msk = 1; msk < 16; msk <<= 1) {
        s1 += __shfl_xor(s1, msk);
        s2 += __shfl_xor(s2, msk);
      }
      float x = e1 / s1, y = e2 / s2;
      int mm = lane & 15, basel = lane & ~15;
      float addv = 0.f, subv = 0.f;
#pragma unroll
      for (int i = 0; i < 16; ++i) {
        float xi = __shfl(x, basel + i);
        float ya = __shfl(y, basel + ((mm - i) & 15));
        float ys = __shfl(y, basel + ((i - mm) & 15));
        addv = fmaf(xi, ya, addv);
        subv = fmaf(xi, ys, subv);
      }
      int q2 = g * 16 + bb2;
      const float* pr = opcode_probs + ((size_t)q2 * LINES + t) * 2;
      float mix = pr[0] * addv + pr[1] * subv;
      st_llc16b(&mixp[((size_t)g * 16 + bb2) * DD + 64 * m + c],
                __builtin_bit_cast(unsigned short, (bf16_t)mix));
    }
    group_barrier(ctr, tid, 16u * (++nbar));   // bar_B: mixp ready

    // ---- Phase G: mix(16x1024) @ w_res(1024x1024), d-slice of this block ----
    {
      const char* base = (const char*)(mixp + (size_t)g * (16 * DD));
#pragma unroll
      for (int c = 0; c < 2; ++c) {
        int ch = tid + c * 1024;
        int row = ch >> 7, k16 = ch & 127;
        u32x4v v = ld_llc_16(base + (size_t)row * 2048 + k16 * 16);
        unsigned byte = (unsigned)(row * 2048 + k16 * 16) ^ ((unsigned)(row & 7) << 4);
        *(u32x4v*)(smem + SM_AT0 + byte) = v;
      }
      __syncthreads();
      const int ns = w & 3, ks = w >> 2;
      const bf16_t* bsrc = wrt + (size_t)(64 * m + ns * 16 + ln15) * DD;
      f32x4 acc = {0.f, 0.f, 0.f, 0.f};
#pragma unroll
      for (int kc = 0; kc < 8; ++kc) {
        int kb = ks * 256 + kc * 32 + kgrp * 8;
        unsigned abyte = ((unsigned)(ln15 * 2048 + kb * 2)) ^ ((unsigned)(ln15 & 7) << 4);
        bf16x8 av = *(const bf16x8*)(smem + SM_AT0 + abyte);
        bf16x8 bv = *(const bf16x8*)(bsrc + kb);
        acc = __builtin_amdgcn_mfma_f32_16x16x32_bf16(av, bv, acc, 0, 0, 0);
      }
      __syncthreads();
      float* red2 = (float*)(smem + SM_RED2);
      if (ks > 0) {
#pragma unroll
        for (int r2 = 0; r2 < 4; ++r2)
          red2[((ks - 1) * 4 + ns) * (16 * 17) + (kgrp * 4 + r2) * 17 + ln15] = acc[r2];
      }
      __syncthreads();
      if (ks == 0) {
        int f = 64 * m + ns * 16 + ln15;
#pragma unroll
        for (int r2 = 0; r2 < 4; ++r2) {
          int crow = kgrp * 4 + r2;
          float v = acc[r2];
#pragma unroll
          for (int kk = 0; kk < 3; ++kk)
            v += red2[(kk * 4 + ns) * (16 * 17) + crow * 17 + ln15];
          st_llc32(&gtw[((size_t)g * 16 + crow) * DD + f],
                   __builtin_bit_cast(unsigned, v + b_res[f]));
        }
      }
    }
    group_barrier(ctr, tid, 16u * (++nbar));   // bar_C: gt ready

    // ---- Phase H: output LN (thread owns d=tid, own batch row) ----
    {
      float xv = __builtin_bit_cast(float, ld_llc32(&gtw[((size_t)g * 16 + m) * DD + tid]));
      float s1 = wred(xv), s2 = wred(xv * xv);
      if (lane == 0) { redp[w * 2] = s1; redp[w * 2 + 1] = s2; }
      __syncthreads();
      float S = 0.f, Q = 0.f;
#pragma unroll
      for (int i = 0; i < 16; ++i) { S += redp[i * 2]; Q += redp[i * 2 + 1]; }
      float mn = S * (1.f / DD), vr = fmaxf(Q * (1.f / DD) - mn * mn, 0.f);
      float vv = (xv - mn) * rsqrtf(vr + EPS) * lno_g[tid] + lno_b[tid];
      float* valp = (float*)(smem + SM_VAL);
      valp[(tid >> 4) * 17 + (tid & 15)] = vv;   // padded: conflict-free redistribution
    }
    __syncthreads();
    // ---- Phase I: gated write-back (pure registers) ----
    {
      float gtv = gate[(size_t)bq * LINES + t];
      const float* valp = (const float*)(smem + SM_VAL);
      float vvj[16];
#pragma unroll
      for (int j = 0; j < 16; ++j) vvj[j] = valp[lane * 17 + j];
#pragma unroll
      for (int rr = 0; rr < 4; ++rr) {
        float gg = gtv * wvp[4 * w + rr];
#pragma unroll
        for (int j = 0; j < 16; ++j)
          Rr_[rr][j] = Rr_[rr][j] * (1.f - gg) + gg * vvj[j];
      }
    }
  }

  // ---- Final: write register-resident R to output (f32, coalesced) ----
  {
    float* Rdst = Rout + (size_t)bq * (NREG * DD);
#pragma unroll
    for (int rr = 0; rr < 4; ++rr) {
#pragma unroll
      for (int c = 0; c < 4; ++c) {
        float4 v;
        v.x = Rr_[rr][c * 4 + 0]; v.y = Rr_[rr][c * 4 + 1];
        v.z = Rr_[rr][c * 4 + 2]; v.w = Rr_[rr][c * 4 + 3];
        *(float4*)(Rdst + (size_t)(4 * w + rr) * DD + lane * 16 + c * 4) = v;
      }
    }
  }
}

// ---------------- fallback (round-1 structure, f32 weights) ----------------
__global__ __launch_bounds__(1024) void interp_fb(
    const float* __restrict__ opcode_probs, const float* __restrict__ k_write,
    const float* __restrict__ q_read, const float* __restrict__ gate,
    const float* __restrict__ ln1_g, const float* __restrict__ ln1_b,
    const float* __restrict__ w1, const float* __restrict__ b1,
    const float* __restrict__ ln2_g, const float* __restrict__ ln2_b,
    const float* __restrict__ w2, const float* __restrict__ b2,
    const float* __restrict__ w_res, const float* __restrict__ b_res,
    const float* __restrict__ lno_g, const float* __restrict__ lno_b,
    float* __restrict__ R) {
  __shared__ float q0s[DD], q1s[DD], kws[DD];
  __shared__ float sc0[NREG], sc1[NREG], scw[NREG];
  __shared__ float at0[NREG], at1[NREG], wv[NREG];
  __shared__ float xn0[DD], xn1[DD];
  __shared__ float mixs[FF];
  __shared__ float val[DD];
  __shared__ float red[64];
  const int b = blockIdx.x;
  const int tid = threadIdx.x;
  const int w = tid >> 6, lane = tid & 63;
  float* Rb = R + (size_t)b * NREG * DD;
  for (int t = 0; t < LINES; ++t) {
    const float* qb = q_read + ((size_t)b * LINES + t) * 2 * DD;
    const float* kb = k_write + ((size_t)b * LINES + t) * DD;
    q0s[tid] = qb[tid]; q1s[tid] = qb[DD + tid]; kws[tid] = kb[tid];
    __syncthreads();
#pragma unroll
    for (int rr = 0; rr < 4; ++rr) {
      int r = w * 4 + rr;
      const float* Rr = Rb + (size_t)r * DD;
      float a0 = 0.f, a1 = 0.f, aw = 0.f;
#pragma unroll
      for (int j = 0; j < 16; ++j) {
        int d = j * 64 + lane;
        float rv = Rr[d];
        a0 += rv * q0s[d]; a1 += rv * q1s[d]; aw += rv * kws[d];
      }
      a0 = wred(a0); a1 = wred(a1); aw = wred(aw);
      if (lane == 0) { sc0[r] = a0 * SCALE; sc1[r] = a1 * SCALE; scw[r] = aw * SCALE; }
    }
    __syncthreads();
    if (w < 3) {
      const float* src = (w == 0) ? sc0 : (w == 1) ? sc1 : scw;
      float* dst = (w == 0) ? at0 : (w == 1) ? at1 : wv;
      float v = src[lane];
      float mx = wmax64(v);
      float e = expf(v - mx);
      float s = wred(e);
      dst[lane] = e / s;
    }
    __syncthreads();
    float os0 = 0.f, os1 = 0.f;
#pragma unroll 4
    for (int r = 0; r < NREG; ++r) {
      float rv = Rb[(size_t)r * DD + tid];
      os0 += at0[r] * rv; os1 += at1[r] * rv;
    }
    {
      float s0 = wred(os0), qq0 = wred(os0 * os0);
      float s1 = wred(os1), qq1 = wred(os1 * os1);
      if (lane == 0) { red[w*4] = s0; red[w*4+1] = qq0; red[w*4+2] = s1; red[w*4+3] = qq1; }
      __syncthreads();
      float S0 = 0, Q0 = 0, S1 = 0, Q1 = 0;
#pragma unroll
      for (int i = 0; i < 16; ++i) { S0 += red[i*4]; Q0 += red[i*4+1]; S1 += red[i*4+2]; Q1 += red[i*4+3]; }
      float m0 = S0 / DD, v0 = fmaxf(Q0 / DD - m0 * m0, 0.f);
      float m1 = S1 / DD, v1 = fmaxf(Q1 / DD - m1 * m1, 0.f);
      xn0[tid] = (os0 - m0) * rsqrtf(v0 + EPS) * ln1_g[tid] + ln1_b[tid];
      xn1[tid] = (os1 - m1) * rsqrtf(v1 + EPS) * ln2_g[tid] + ln2_b[tid];
      __syncthreads();
    }
    float p1v = b1[tid], p2v = b2[tid];
    {
      const float* c1 = w1 + tid;
      const float* c2 = w2 + tid;
#pragma unroll 4
      for (int d = 0; d < DD; ++d) {
        p1v += xn0[d] * c1[(size_t)d * FF];
        p2v += xn1[d] * c2[(size_t)d * FF];
      }
    }
    {
      int mmm = lane & 15, basel = lane & ~15;
      float mx1 = p1v, mx2 = p2v;
      for (int msk = 1; msk < 16; msk <<= 1) {
        mx1 = fmaxf(mx1, __shfl_xor(mx1, msk));
        mx2 = fmaxf(mx2, __shfl_xor(mx2, msk));
      }
      float e1 = expf(p1v - mx1), e2 = expf(p2v - mx2);
      float s1 = e1, s2 = e2;
      for (int msk = 1; msk < 16; msk <<= 1) { s1 += __shfl_xor(s1, msk); s2 += __shfl_xor(s2, msk); }
      float x = e1 / s1, y = e2 / s2;
      float addv = 0.f, subv = 0.f;
#pragma unroll
      for (int i = 0; i < 16; ++i) {
        float xi = __shfl(x, basel + i);
        float ya = __shfl(y, basel + ((mmm - i) & 15));
        float ys = __shfl(y, basel + ((i - mmm) & 15));
        addv += xi * ya; subv += xi * ys;
      }
      const float* pr = opcode_probs + ((size_t)b * LINES + t) * 2;
      mixs[tid] = pr[0] * addv + pr[1] * subv;
    }
    __syncthreads();
    float acc = b_res[tid];
    {
      const float* cr = w_res + tid;
#pragma unroll 4
      for (int f = 0; f < FF; ++f) acc += mixs[f] * cr[(size_t)f * DD];
    }
    {
      float s1 = wred(acc), s2 = wred(acc * acc);
      if (lane == 0) { red[w*2] = s1; red[w*2+1] = s2; }
      __syncthreads();
      float S = 0, Q = 0;
#pragma unroll
      for (int i = 0; i < 16; ++i) { S += red[i*2]; Q += red[i*2+1]; }
      float mn = S / DD, vr = fmaxf(Q / DD - mn * mn, 0.f);
      val[tid] = (acc - mn) * rsqrtf(vr + EPS) * lno_g[tid] + lno_b[tid];
      __syncthreads();
    }
    {
      float gt_ = gate[(size_t)b * LINES + t];
      float vv = val[tid];
#pragma unroll 4
      for (int r = 0; r < NREG; ++r) {
        float gg = gt_ * wv[r];
        size_t idx = (size_t)r * DD + tid;
        Rb[idx] = Rb[idx] * (1.f - gg) + gg * vv;
      }
    }
    __syncthreads();
  }
}

extern "C" void kernel_launch(void* const* d_in, const int* in_sizes, int n_in,
                              void* d_out, int out_size, void* d_ws, size_t ws_size,
                              hipStream_t stream) {
  const float* opcode = (const float*)d_in[0];
  const float* registers = (const float*)d_in[1];
  const float* k_write = (const float*)d_in[2];
  const float* q_read = (const float*)d_in[3];
  const float* gate = (const float*)d_in[5];
  const float* ln1_g = (const float*)d_in[6];
  const float* ln1_b = (const float*)d_in[7];
  const float* w1 = (const float*)d_in[8];
  const float* b1 = (const float*)d_in[9];
  const float* ln2_g = (const float*)d_in[10];
  const float* ln2_b = (const float*)d_in[11];
  const float* w2 = (const float*)d_in[12];
  const float* b2 = (const float*)d_in[13];
  const float* w_res = (const float*)d_in[14];
  const float* b_res = (const float*)d_in[15];
  const float* lno_g = (const float*)d_in[16];
  const float* lno_b = (const float*)d_in[17];
  float* R = (float*)d_out;

  if (ws_size >= (size_t)WS_NEED) {
    transcvt<<<dim3(16, 16, 3), 256, 0, stream>>>(w1, w2, w_res, (bf16_t*)d_ws);
    hipMemsetAsync((char*)d_ws + WS_CTR, 0, 1024, stream);
    interp3<<<BB, 1024, 0, stream>>>(opcode, registers, k_write, q_read, gate,
                                     ln1_g, ln1_b, b1, ln2_g, ln2_b, b2,
                                     b_res, lno_g, lno_b, (char*)d_ws, R);
  } else {
    hipMemcpyAsync(R, registers, (size_t)BB * NREG * DD * sizeof(float),
                   hipMemcpyDeviceToDevice, stream);
    interp_fb<<<BB, 1024, 0, stream>>>(opcode, k_write, q_read, gate, ln1_g, ln1_b,
                                       w1, b1, ln2_g, ln2_b, w2, b2, w_res, b_res,
                                       lno_g, lno_b, R);
  }
}

// Round 6
// 3953.170 us; speedup vs baseline: 3.3316x; 1.0468x over previous
//
#include <hip/hip_runtime.h>
#include <hip/hip_bf16.h>

#define BB 256
#define LINES 64
#define NREG 64
#define DD 1024
#define FF 1024

constexpr float EPS = 1e-5f;
constexpr float SCALE = 0.03125f; // 1/sqrt(1024)

typedef __bf16 bf16_t;
typedef bf16_t bf16x8 __attribute__((ext_vector_type(8)));
typedef unsigned short us16x8 __attribute__((ext_vector_type(8)));
typedef float f32x4 __attribute__((ext_vector_type(4)));
typedef unsigned u32x4v __attribute__((ext_vector_type(4)));
typedef unsigned long long u64;

// ---------------- d_ws layout (bytes) ----------------
#define WS_W1T   0u                         // w1^T  [f][d] bf16, 2MB
#define WS_W2T   (2u << 20)                 // w2^T  [f][d] bf16, 2MB
#define WS_WRT   (4u << 20)                 // w_res^T [d][f] bf16, 2MB
#define WS_XNP   (6u << 20)                 // xnp [16g][16j][1024] u32 (bf16 xn0|xn1), 1MB
#define WS_MIXP  (7u << 20)                 // mixp [16g][16][1024] bf16, 512KB
#define WS_GT    ((7u << 20) + (1u << 19))  // gt  [16g][16][1024] f32, 1MB
#define WS_CTR   ((8u << 20) + (1u << 19))  // 16 counters x 64B
#define WS_NEED  (WS_CTR + 1024u)

// ---------------- LDS layout (bytes) ----------------
#define SM_WV    0
#define SM_AT0P  256
#define SM_AT1P  512
#define SM_SC0   768
#define SM_SC1   1024
#define SM_SCW   1280
#define SM_RED   1536
#define SM_DYN   2048
#define SM_OSB   SM_DYN                     // [16][1088] f32 = 69632B (aliases AT0/AT1; disjoint in time)
#define SM_AT0   SM_DYN                     // 32KB bf16 [16][1024] XOR-swizzled (xn0 / mix tile)
#define SM_AT1   (SM_DYN + 32768)           // 32KB tile for xn1
#define SM_RED2  (SM_DYN + 65536)           // [3][4][16][17] f32 = 13056B
#define SM_PRE   (SM_DYN + 65536 + 13056)   // [2][16][66] f32 = 8448B
#define SM_VAL   (SM_DYN + 65536 + 13056 + 8448)  // [64*17] f32 padded = 4352B
#define SM_QPF   (SM_VAL + 4352)            // 3 x [64*20] f32 padded = 15360B (q0,q1,kw prefetch)
#define SM_SIZE  (SM_QPF + 15360)

__device__ __forceinline__ float wred(float v) {
#pragma unroll
  for (int m = 32; m >= 1; m >>= 1) v += __shfl_xor(v, m);
  return v;
}
__device__ __forceinline__ float wmax64(float v) {
#pragma unroll
  for (int m = 32; m >= 1; m >>= 1) v = fmaxf(v, __shfl_xor(v, m));
  return v;
}

// ---- LLC-coherent (sc0 sc1) access helpers: bypass L1 and non-coherent XCD L2 ----
__device__ __forceinline__ void st_llc32(void* p, unsigned v) {
  asm volatile("global_store_dword %0, %1, off sc0 sc1" :: "v"(p), "v"(v) : "memory");
}
__device__ __forceinline__ void st_llc16b(void* p, unsigned short v) {
  unsigned vv = v;
  asm volatile("global_store_short %0, %1, off sc0 sc1" :: "v"(p), "v"(vv) : "memory");
}
__device__ __forceinline__ unsigned ld_llc32(const void* p) {
  unsigned r;
  asm volatile("global_load_dword %0, %1, off sc0 sc1\n\ts_waitcnt vmcnt(0)"
               : "=v"(r) : "v"(p) : "memory");
  return r;
}
// no-wait variants: caller must execute wait_vm0() + sched_barrier before use
__device__ __forceinline__ void ld_llc_4x8_nw(const void* p, u64& a, u64& b, u64& c, u64& d) {
  asm volatile(
      "global_load_dwordx2 %0, %4, off sc0 sc1\n\t"
      "global_load_dwordx2 %1, %4, off offset:8 sc0 sc1\n\t"
      "global_load_dwordx2 %2, %4, off offset:16 sc0 sc1\n\t"
      "global_load_dwordx2 %3, %4, off offset:24 sc0 sc1"
      : "=&v"(a), "=&v"(b), "=&v"(c), "=&v"(d) : "v"(p) : "memory");
}
__device__ __forceinline__ void ld_llc_16_nw(const void* p, u32x4v& r) {
  asm volatile("global_load_dwordx4 %0, %1, off sc0 sc1"
               : "=&v"(r) : "v"(p) : "memory");
}
__device__ __forceinline__ void wait_vm0() {
  asm volatile("s_waitcnt vmcnt(0)" ::: "memory");
  __builtin_amdgcn_sched_barrier(0);   // rule #18: keep dependent VALU below the wait
}

// Fence-free group barrier (validated rounds 4-5): producer drains vmcnt ->
// syncthreads -> tid0 relaxed agent atomic (RMW at LLC); consumer spins on
// sc0sc1 load; data moves exclusively via sc0sc1 accesses. No cache flushes.
__device__ __forceinline__ void group_barrier(unsigned* ctr, int tid, unsigned target) {
  asm volatile("s_waitcnt vmcnt(0)" ::: "memory");
  __syncthreads();
  if (tid == 0) {
    __hip_atomic_fetch_add(ctr, 1u, __ATOMIC_RELAXED, __HIP_MEMORY_SCOPE_AGENT);
    while (ld_llc32(ctr) < target) __builtin_amdgcn_s_sleep(2);
  }
  __syncthreads();
}

// transpose + f32->bf16: dst[j][i] = src[i][j], 1024x1024; z selects matrix
__global__ __launch_bounds__(256) void transcvt(const float* __restrict__ w1,
                                                const float* __restrict__ w2,
                                                const float* __restrict__ wr,
                                                bf16_t* __restrict__ out) {
  __shared__ float tl[64][65];
  const float* src = (blockIdx.z == 0) ? w1 : (blockIdx.z == 1) ? w2 : wr;
  bf16_t* dst = out + (size_t)blockIdx.z * (1u << 20);
  const int i0 = blockIdx.x * 64, j0 = blockIdx.y * 64;
  const int t = threadIdx.x;
#pragma unroll
  for (int it = 0; it < 4; ++it) {
    int r = (t >> 4) + it * 16;
    int c4 = (t & 15) * 4;
    const float4 v = *reinterpret_cast<const float4*>(&src[(size_t)(i0 + r) * 1024 + j0 + c4]);
    tl[r][c4] = v.x; tl[r][c4 + 1] = v.y; tl[r][c4 + 2] = v.z; tl[r][c4 + 3] = v.w;
  }
  __syncthreads();
  const int orow = t >> 2, seg = t & 3;
  bf16x8 v0, v1;
#pragma unroll
  for (int u = 0; u < 8; ++u) {
    v0[u] = (bf16_t)tl[seg * 16 + u][orow];
    v1[u] = (bf16_t)tl[seg * 16 + 8 + u][orow];
  }
  bf16_t* dp = dst + (size_t)(j0 + orow) * 1024 + i0 + seg * 16;
  *reinterpret_cast<bf16x8*>(dp) = v0;
  *reinterpret_cast<bf16x8*>(dp + 8) = v1;
}

__global__ __launch_bounds__(1024, 4) void interp3(
    const float* __restrict__ opcode_probs, const float* __restrict__ Rin,
    const float* __restrict__ k_write, const float* __restrict__ q_read,
    const float* __restrict__ gate,
    const float* __restrict__ ln1_g, const float* __restrict__ ln1_b, const float* __restrict__ b1,
    const float* __restrict__ ln2_g, const float* __restrict__ ln2_b, const float* __restrict__ b2,
    const float* __restrict__ b_res, const float* __restrict__ lno_g, const float* __restrict__ lno_b,
    char* __restrict__ ws, float* __restrict__ Rout) {
  __shared__ __align__(16) char smem[SM_SIZE];
  float* wvp  = (float*)(smem + SM_WV);
  float* at0p = (float*)(smem + SM_AT0P);
  float* at1p = (float*)(smem + SM_AT1P);
  float* sc0p = (float*)(smem + SM_SC0);
  float* sc1p = (float*)(smem + SM_SC1);
  float* scwp = (float*)(smem + SM_SCW);
  float* redp = (float*)(smem + SM_RED);

  const int b = blockIdx.x;
  const int g = b >> 4;                   // group: consecutive blocks 16g..16g+15
  const int j = b & 15;                   // batch row within group (bq = 16g+j = b)
  // weight-slice id: permutation of 0..15 within each group, keyed to b%8 so
  // that (under round-robin block->XCD dispatch) each XCD touches only 2
  // slices (768KB of weights) -> L2-resident.
  const int m = ((b & 7) << 1) | ((b >> 3) & 1);
  const int bq = b;
  const int tid = threadIdx.x;
  const int w = tid >> 6, lane = tid & 63;
  const int ln15 = lane & 15, kgrp = lane >> 4;

  const bf16_t* w1t = (const bf16_t*)(ws + WS_W1T);
  const bf16_t* w2t = (const bf16_t*)(ws + WS_W2T);
  const bf16_t* wrt = (const bf16_t*)(ws + WS_WRT);
  unsigned* xnp   = (unsigned*)(ws + WS_XNP);   // packed (bf16 xn0 | bf16 xn1)
  bf16_t*  mixp   = (bf16_t*)(ws + WS_MIXP);
  unsigned* gtw   = (unsigned*)(ws + WS_GT);    // f32 bits
  unsigned* ctr   = (unsigned*)(ws + WS_CTR) + g * 16;

  // R rows [4w, 4w+4), columns [16*lane, 16*lane+16) live in registers.
  float Rr_[4][16];
  {
    const float* Rsrc = Rin + (size_t)bq * (NREG * DD);
#pragma unroll
    for (int rr = 0; rr < 4; ++rr) {
#pragma unroll
      for (int c = 0; c < 4; ++c) {
        float4 v = *(const float4*)(Rsrc + (size_t)(4 * w + rr) * DD + lane * 16 + c * 4);
        Rr_[rr][c * 4 + 0] = v.x; Rr_[rr][c * 4 + 1] = v.y;
        Rr_[rr][c * 4 + 2] = v.z; Rr_[rr][c * 4 + 3] = v.w;
      }
    }
  }

  // Prologue: stage step-0 q0/q1/kw into padded LDS prefetch buffers.
  {
    const float* qb = q_read + ((size_t)bq * LINES + 0) * (2 * DD);
    const float* kb = k_write + ((size_t)bq * LINES + 0) * DD;
    float* qpf = (float*)(smem + SM_QPF);
    const int pidx = (tid >> 4) * 20 + (tid & 15);
    qpf[pidx] = qb[tid];
    qpf[1280 + pidx] = qb[DD + tid];
    qpf[2560 + pidx] = kb[tid];
  }
  __syncthreads();

  unsigned nbar = 0;

  for (int t = 0; t < LINES; ++t) {
    // ---- Phase A: attention scores from register-resident R; q from LDS ----
    {
      const float* qpf = (const float*)(smem + SM_QPF);
      const int pb = lane * 20;
#pragma unroll
      for (int v = 0; v < 3; ++v) {
        float* dst = (v == 0) ? sc0p : (v == 1) ? sc1p : scwp;
        float qv[16];
#pragma unroll
        for (int c = 0; c < 4; ++c) {
          float4 t4 = *(const float4*)(qpf + v * 1280 + pb + c * 4);
          qv[c * 4 + 0] = t4.x; qv[c * 4 + 1] = t4.y;
          qv[c * 4 + 2] = t4.z; qv[c * 4 + 3] = t4.w;
        }
#pragma unroll
        for (int rr = 0; rr < 4; ++rr) {
          float s = 0.f;
#pragma unroll
          for (int jj = 0; jj < 16; ++jj) s = fmaf(Rr_[rr][jj], qv[jj], s);
          s = wred(s);
          if (lane == 0) dst[4 * w + rr] = s * SCALE;
        }
      }
    }
    __syncthreads();
    // ---- Phase B: three 64-wide softmaxes ----
    if (w < 3) {
      const float* src = (w == 0) ? sc0p : (w == 1) ? sc1p : scwp;
      float* dst = (w == 0) ? at0p : (w == 1) ? at1p : wvp;
      float v = src[lane];
      float mx = wmax64(v);
      float e = expf(v - mx);
      float s = wred(e);
      dst[lane] = e / s;
    }
    __syncthreads();
    // ---- Phase C: op_s via register FMAs + padded-LDS cross-wave reduce ----
    float os0, os1;
    {
      float p0[16], p1[16];
#pragma unroll
      for (int jj = 0; jj < 16; ++jj) { p0[jj] = 0.f; p1[jj] = 0.f; }
#pragma unroll
      for (int rr = 0; rr < 4; ++rr) {
        float a0 = at0p[4 * w + rr], a1 = at1p[4 * w + rr];
#pragma unroll
        for (int jj = 0; jj < 16; ++jj) {
          p0[jj] = fmaf(a0, Rr_[rr][jj], p0[jj]);
          p1[jj] = fmaf(a1, Rr_[rr][jj], p1[jj]);
        }
      }
      float* osb = (float*)(smem + SM_OSB);
      const int rp = (tid >> 4) * 17 + (tid & 15);
#pragma unroll
      for (int jj = 0; jj < 16; ++jj) osb[w * 1088 + lane * 17 + jj] = p0[jj];
      __syncthreads();
      os0 = 0.f;
#pragma unroll
      for (int ww = 0; ww < 16; ++ww) os0 += osb[ww * 1088 + rp];
      __syncthreads();
#pragma unroll
      for (int jj = 0; jj < 16; ++jj) osb[w * 1088 + lane * 17 + jj] = p1[jj];
      __syncthreads();
      os1 = 0.f;
#pragma unroll
      for (int ww = 0; ww < 16; ++ww) os1 += osb[ww * 1088 + rp];
    }
    // ---- Phase D: LN1/LN2 -> xnp row j (packed bf16 pair, LLC store) ----
    {
      float s0 = wred(os0), qq0 = wred(os0 * os0);
      float s1 = wred(os1), qq1 = wred(os1 * os1);
      if (lane == 0) { redp[w*4] = s0; redp[w*4+1] = qq0; redp[w*4+2] = s1; redp[w*4+3] = qq1; }
      __syncthreads();
      float S0 = 0, Q0 = 0, S1 = 0, Q1 = 0;
#pragma unroll
      for (int i = 0; i < 16; ++i) { S0 += redp[i*4]; Q0 += redp[i*4+1]; S1 += redp[i*4+2]; Q1 += redp[i*4+3]; }
      float m0 = S0 * (1.f / DD), v0 = fmaxf(Q0 * (1.f / DD) - m0 * m0, 0.f);
      float m1 = S1 * (1.f / DD), v1 = fmaxf(Q1 * (1.f / DD) - m1 * m1, 0.f);
      float xn0v = (os0 - m0) * rsqrtf(v0 + EPS) * ln1_g[tid] + ln1_b[tid];
      float xn1v = (os1 - m1) * rsqrtf(v1 + EPS) * ln2_g[tid] + ln2_b[tid];
      unsigned pw = (unsigned)__builtin_bit_cast(unsigned short, (bf16_t)xn0v)
                  | ((unsigned)__builtin_bit_cast(unsigned short, (bf16_t)xn1v) << 16);
      st_llc32(&xnp[((size_t)g * 16 + j) * DD + tid], pw);
    }
    group_barrier(ctr, tid, 16u * (++nbar));   // bar_A: xnp ready

    // ---- Stage BOTH A-tiles (xn0 -> AT0, xn1 -> AT1), batched loads ----
    {
      const char* base = (const char*)(xnp + (size_t)g * (16 * DD));
      const int row = tid >> 7, k16 = tid & 127;  // rows 0-7; +8 for second half
      u64 a0, a1, a2, a3, c0, c1, c2, c3;
      ld_llc_4x8_nw(base + (size_t)row * 4096 + k16 * 32, a0, a1, a2, a3);
      ld_llc_4x8_nw(base + (size_t)(row + 8) * 4096 + k16 * 32, c0, c1, c2, c3);
      wait_vm0();
#pragma unroll
      for (int h = 0; h < 2; ++h) {
        u64 x0 = h ? c0 : a0, x1 = h ? c1 : a1, x2 = h ? c2 : a2, x3 = h ? c3 : a3;
        int r = row + h * 8;
        us16x8 v0, v1;
        v0[0] = (unsigned short)x0;         v1[0] = (unsigned short)(x0 >> 16);
        v0[1] = (unsigned short)(x0 >> 32); v1[1] = (unsigned short)(x0 >> 48);
        v0[2] = (unsigned short)x1;         v1[2] = (unsigned short)(x1 >> 16);
        v0[3] = (unsigned short)(x1 >> 32); v1[3] = (unsigned short)(x1 >> 48);
        v0[4] = (unsigned short)x2;         v1[4] = (unsigned short)(x2 >> 16);
        v0[5] = (unsigned short)(x2 >> 32); v1[5] = (unsigned short)(x2 >> 48);
        v0[6] = (unsigned short)x3;         v1[6] = (unsigned short)(x3 >> 16);
        v0[7] = (unsigned short)(x3 >> 32); v1[7] = (unsigned short)(x3 >> 48);
        unsigned byte = (unsigned)(r * 2048 + k16 * 16) ^ ((unsigned)(r & 7) << 4);
        *(us16x8*)(smem + SM_AT0 + byte) = v0;
        *(us16x8*)(smem + SM_AT1 + byte) = v1;
      }
    }
    // prefetch next step's q0/q1/kw (plain cached loads; consumed in Phase I)
    float pf0, pf1, pf2;
    {
      int tn = (t + 1 < LINES) ? (t + 1) : (LINES - 1);
      const float* qb2 = q_read + ((size_t)bq * LINES + tn) * (2 * DD);
      const float* kb2 = k_write + ((size_t)bq * LINES + tn) * DD;
      pf0 = qb2[tid]; pf1 = qb2[DD + tid]; pf2 = kb2[tid];
    }
    __syncthreads();

    // ---- Phase E: two 16x1024 @ 1024x64 MFMA GEMMs (f-slice m of this block) ----
#pragma unroll
    for (int gm = 0; gm < 2; ++gm) {
      const char* atile = smem + (gm ? SM_AT1 : SM_AT0);
      const int ns = w & 3, ks = w >> 2;          // 4 n-subtiles x 4 k-splits
      const bf16_t* bsrc = (gm ? w2t : w1t) + (size_t)(64 * m + ns * 16 + ln15) * DD;
      f32x4 acc = {0.f, 0.f, 0.f, 0.f};
#pragma unroll
      for (int kc = 0; kc < 8; ++kc) {
        int kb = ks * 256 + kc * 32 + kgrp * 8;
        unsigned abyte = ((unsigned)(ln15 * 2048 + kb * 2)) ^ ((unsigned)(ln15 & 7) << 4);
        bf16x8 av = *(const bf16x8*)(atile + abyte);
        bf16x8 bv = *(const bf16x8*)(bsrc + kb);
        acc = __builtin_amdgcn_mfma_f32_16x16x32_bf16(av, bv, acc, 0, 0, 0);
      }
      __syncthreads();
      float* red2 = (float*)(smem + SM_RED2);
      if (ks > 0) {
#pragma unroll
        for (int r2 = 0; r2 < 4; ++r2)
          red2[((ks - 1) * 4 + ns) * (16 * 17) + (kgrp * 4 + r2) * 17 + ln15] = acc[r2];
      }
      __syncthreads();
      if (ks == 0) {
        float* prep = (float*)(smem + SM_PRE) + gm * (16 * 66);
#pragma unroll
        for (int r2 = 0; r2 < 4; ++r2) {
          int crow = kgrp * 4 + r2;
          float v = acc[r2];
#pragma unroll
          for (int kk = 0; kk < 3; ++kk)
            v += red2[(kk * 4 + ns) * (16 * 17) + crow * 17 + ln15];
          prep[crow * 66 + ns * 16 + ln15] = v;
        }
      }
      __syncthreads();
    }
    // ---- Phase F: per-16 softmax + modular digit conv; wave w = batch-row w ----
    {
      float* prep = (float*)(smem + SM_PRE);
      const int bb2 = w, c = lane;
      float xp = prep[bb2 * 66 + c] + b1[64 * m + c];
      float yp = prep[16 * 66 + bb2 * 66 + c] + b2[64 * m + c];
      float mx1 = xp, mx2 = yp;
#pragma unroll
      for (int msk = 1; msk < 16; msk <<= 1) {
        mx1 = fmaxf(mx1, __shfl_xor(mx1, msk));
        mx2 = fmaxf(mx2, __shfl_xor(mx2, msk));
      }
      float e1 = expf(xp - mx1), e2 = expf(yp - mx2);
      float s1 = e1, s2 = e2;
#pragma unroll
      for (int msk = 1; msk < 16; msk <<= 1) {
        s1 += __shfl_xor(s1, msk);
        s2 += __shfl_xor(s2, msk);
      }
      float x = e1 / s1, y = e2 / s2;
      int mm = lane & 15, basel = lane & ~15;
      float addv = 0.f, subv = 0.f;
#pragma unroll
      for (int i = 0; i < 16; ++i) {
        float xi = __shfl(x, basel + i);
        float ya = __shfl(y, basel + ((mm - i) & 15));
        float ys = __shfl(y, basel + ((i - mm) & 15));
        addv = fmaf(xi, ya, addv);
        subv = fmaf(xi, ys, subv);
      }
      int q2 = g * 16 + bb2;
      const float* pr = opcode_probs + ((size_t)q2 * LINES + t) * 2;
      float mix = pr[0] * addv + pr[1] * subv;
      st_llc16b(&mixp[((size_t)g * 16 + bb2) * DD + 64 * m + c],
                __builtin_bit_cast(unsigned short, (bf16_t)mix));
    }
    group_barrier(ctr, tid, 16u * (++nbar));   // bar_B: mixp ready

    // ---- Phase G: mix(16x1024) @ w_res(1024x1024), d-slice m of this block ----
    {
      const char* base = (const char*)(mixp + (size_t)g * (16 * DD));
      const int row = tid >> 7, k16 = tid & 127;
      u32x4v va, vb;
      ld_llc_16_nw(base + (size_t)row * 2048 + k16 * 16, va);
      ld_llc_16_nw(base + (size_t)(row + 8) * 2048 + k16 * 16, vb);
      wait_vm0();
      unsigned byte0 = (unsigned)(row * 2048 + k16 * 16) ^ ((unsigned)(row & 7) << 4);
      unsigned byte1 = (unsigned)((row + 8) * 2048 + k16 * 16) ^ ((unsigned)(row & 7) << 4);
      *(u32x4v*)(smem + SM_AT0 + byte0) = va;
      *(u32x4v*)(smem + SM_AT0 + byte1) = vb;
      __syncthreads();
      const int ns = w & 3, ks = w >> 2;
      const bf16_t* bsrc = wrt + (size_t)(64 * m + ns * 16 + ln15) * DD;
      f32x4 acc = {0.f, 0.f, 0.f, 0.f};
#pragma unroll
      for (int kc = 0; kc < 8; ++kc) {
        int kb = ks * 256 + kc * 32 + kgrp * 8;
        unsigned abyte = ((unsigned)(ln15 * 2048 + kb * 2)) ^ ((unsigned)(ln15 & 7) << 4);
        bf16x8 av = *(const bf16x8*)(smem + SM_AT0 + abyte);
        bf16x8 bv = *(const bf16x8*)(bsrc + kb);
        acc = __builtin_amdgcn_mfma_f32_16x16x32_bf16(av, bv, acc, 0, 0, 0);
      }
      __syncthreads();
      float* red2 = (float*)(smem + SM_RED2);
      if (ks > 0) {
#pragma unroll
        for (int r2 = 0; r2 < 4; ++r2)
          red2[((ks - 1) * 4 + ns) * (16 * 17) + (kgrp * 4 + r2) * 17 + ln15] = acc[r2];
      }
      __syncthreads();
      if (ks == 0) {
        int f = 64 * m + ns * 16 + ln15;
#pragma unroll
        for (int r2 = 0; r2 < 4; ++r2) {
          int crow = kgrp * 4 + r2;
          float v = acc[r2];
#pragma unroll
          for (int kk = 0; kk < 3; ++kk)
            v += red2[(kk * 4 + ns) * (16 * 17) + crow * 17 + ln15];
          st_llc32(&gtw[((size_t)g * 16 + crow) * DD + f],
                   __builtin_bit_cast(unsigned, v + b_res[f]));
        }
      }
    }
    group_barrier(ctr, tid, 16u * (++nbar));   // bar_C: gt ready

    // ---- Phase H: output LN on own batch row j ----
    {
      float xv = __builtin_bit_cast(float, ld_llc32(&gtw[((size_t)g * 16 + j) * DD + tid]));
      float s1 = wred(xv), s2 = wred(xv * xv);
      if (lane == 0) { redp[w * 2] = s1; redp[w * 2 + 1] = s2; }
      __syncthreads();
      float S = 0.f, Q = 0.f;
#pragma unroll
      for (int i = 0; i < 16; ++i) { S += redp[i * 2]; Q += redp[i * 2 + 1]; }
      float mn = S * (1.f / DD), vr = fmaxf(Q * (1.f / DD) - mn * mn, 0.f);
      float vv = (xv - mn) * rsqrtf(vr + EPS) * lno_g[tid] + lno_b[tid];
      float* valp = (float*)(smem + SM_VAL);
      valp[(tid >> 4) * 17 + (tid & 15)] = vv;   // padded: conflict-free redistribution
    }
    __syncthreads();
    // ---- Phase I: gated write-back (pure registers) + qpf stage for t+1 ----
    {
      float gtv = gate[(size_t)bq * LINES + t];
      const float* valp = (const float*)(smem + SM_VAL);
      float vvj[16];
#pragma unroll
      for (int jj = 0; jj < 16; ++jj) vvj[jj] = valp[lane * 17 + jj];
#pragma unroll
      for (int rr = 0; rr < 4; ++rr) {
        float gg = gtv * wvp[4 * w + rr];
#pragma unroll
        for (int jj = 0; jj < 16; ++jj)
          Rr_[rr][jj] = Rr_[rr][jj] * (1.f - gg) + gg * vvj[jj];
      }
      float* qpf = (float*)(smem + SM_QPF);
      const int pidx = (tid >> 4) * 20 + (tid & 15);
      qpf[pidx] = pf0;
      qpf[1280 + pidx] = pf1;
      qpf[2560 + pidx] = pf2;
    }
    __syncthreads();   // qpf visible for next iteration's Phase A
  }

  // ---- Final: write register-resident R to output (f32, coalesced) ----
  {
    float* Rdst = Rout + (size_t)bq * (NREG * DD);
#pragma unroll
    for (int rr = 0; rr < 4; ++rr) {
#pragma unroll
      for (int c = 0; c < 4; ++c) {
        float4 v;
        v.x = Rr_[rr][c * 4 + 0]; v.y = Rr_[rr][c * 4 + 1];
        v.z = Rr_[rr][c * 4 + 2]; v.w = Rr_[rr][c * 4 + 3];
        *(float4*)(Rdst + (size_t)(4 * w + rr) * DD + lane * 16 + c * 4) = v;
      }
    }
  }
}

// ---------------- fallback (round-1 structure, f32 weights) ----------------
__global__ __launch_bounds__(1024) void interp_fb(
    const float* __restrict__ opcode_probs, const float* __restrict__ k_write,
    const float* __restrict__ q_read, const float* __restrict__ gate,
    const float* __restrict__ ln1_g, const float* __restrict__ ln1_b,
    const float* __restrict__ w1, const float* __restrict__ b1,
    const float* __restrict__ ln2_g, const float* __restrict__ ln2_b,
    const float* __restrict__ w2, const float* __restrict__ b2,
    const float* __restrict__ w_res, const float* __restrict__ b_res,
    const float* __restrict__ lno_g, const float* __restrict__ lno_b,
    float* __restrict__ R) {
  __shared__ float q0s[DD], q1s[DD], kws[DD];
  __shared__ float sc0[NREG], sc1[NREG], scw[NREG];
  __shared__ float at0[NREG], at1[NREG], wv[NREG];
  __shared__ float xn0[DD], xn1[DD];
  __shared__ float mixs[FF];
  __shared__ float val[DD];
  __shared__ float red[64];
  const int b = blockIdx.x;
  const int tid = threadIdx.x;
  const int w = tid >> 6, lane = tid & 63;
  float* Rb = R + (size_t)b * NREG * DD;
  for (int t = 0; t < LINES; ++t) {
    const float* qb = q_read + ((size_t)b * LINES + t) * 2 * DD;
    const float* kb = k_write + ((size_t)b * LINES + t) * DD;
    q0s[tid] = qb[tid]; q1s[tid] = qb[DD + tid]; kws[tid] = kb[tid];
    __syncthreads();
#pragma unroll
    for (int rr = 0; rr < 4; ++rr) {
      int r = w * 4 + rr;
      const float* Rr = Rb + (size_t)r * DD;
      float a0 = 0.f, a1 = 0.f, aw = 0.f;
#pragma unroll
      for (int jj = 0; jj < 16; ++jj) {
        int d = jj * 64 + lane;
        float rv = Rr[d];
        a0 += rv * q0s[d]; a1 += rv * q1s[d]; aw += rv * kws[d];
      }
      a0 = wred(a0); a1 = wred(a1); aw = wred(aw);
      if (lane == 0) { sc0[r] = a0 * SCALE; sc1[r] = a1 * SCALE; scw[r] = aw * SCALE; }
    }
    __syncthreads();
    if (w < 3) {
      const float* src = (w == 0) ? sc0 : (w == 1) ? sc1 : scw;
      float* dst = (w == 0) ? at0 : (w == 1) ? at1 : wv;
      float v = src[lane];
      float mx = wmax64(v);
      float e = expf(v - mx);
      float s = wred(e);
      dst[lane] = e / s;
    }
    __syncthreads();
    float os0 = 0.f, os1 = 0.f;
#pragma unroll 4
    for (int r = 0; r < NREG; ++r) {
      float rv = Rb[(size_t)r * DD + tid];
      os0 += at0[r] * rv; os1 += at1[r] * rv;
    }
    {
      float s0 = wred(os0), qq0 = wred(os0 * os0);
      float s1 = wred(os1), qq1 = wred(os1 * os1);
      if (lane == 0) { red[w*4] = s0; red[w*4+1] = qq0; red[w*4+2] = s1; red[w*4+3] = qq1; }
      __syncthreads();
      float S0 = 0, Q0 = 0, S1 = 0, Q1 = 0;
#pragma unroll
      for (int i = 0; i < 16; ++i) { S0 += red[i*4]; Q0 += red[i*4+1]; S1 += red[i*4+2]; Q1 += red[i*4+3]; }
      float m0 = S0 / DD, v0 = fmaxf(Q0 / DD - m0 * m0, 0.f);
      float m1 = S1 / DD, v1 = fmaxf(Q1 / DD - m1 * m1, 0.f);
      xn0[tid] = (os0 - m0) * rsqrtf(v0 + EPS) * ln1_g[tid] + ln1_b[tid];
      xn1[tid] = (os1 - m1) * rsqrtf(v1 + EPS) * ln2_g[tid] + ln2_b[tid];
      __syncthreads();
    }
    float p1v = b1[tid], p2v = b2[tid];
    {
      const float* c1 = w1 + tid;
      const float* c2 = w2 + tid;
#pragma unroll 4
      for (int d = 0; d < DD; ++d) {
        p1v += xn0[d] * c1[(size_t)d * FF];
        p2v += xn1[d] * c2[(size_t)d * FF];
      }
    }
    {
      int mmm = lane & 15, basel = lane & ~15;
      float mx1 = p1v, mx2 = p2v;
      for (int msk = 1; msk < 16; msk <<= 1) {
        mx1 = fmaxf(mx1, __shfl_xor(mx1, msk));
        mx2 = fmaxf(mx2, __shfl_xor(mx2, msk));
      }
      float e1 = expf(p1v - mx1), e2 = expf(p2v - mx2);
      float s1 = e1, s2 = e2;
      for (int msk = 1; msk < 16; msk <<= 1) { s1 += __shfl_xor(s1, msk); s2 += __shfl_xor(s2, msk); }
      float x = e1 / s1, y = e2 / s2;
      float addv = 0.f, subv = 0.f;
#pragma unroll
      for (int i = 0; i < 16; ++i) {
        float xi = __shfl(x, basel + i);
        float ya = __shfl(y, basel + ((mmm - i) & 15));
        float ys = __shfl(y, basel + ((i - mmm) & 15));
        addv += xi * ya; subv += xi * ys;
      }
      const float* pr = opcode_probs + ((size_t)b * LINES + t) * 2;
      mixs[tid] = pr[0] * addv + pr[1] * subv;
    }
    __syncthreads();
    float acc = b_res[tid];
    {
      const float* cr = w_res + tid;
#pragma unroll 4
      for (int f = 0; f < FF; ++f) acc += mixs[f] * cr[(size_t)f * DD];
    }
    {
      float s1 = wred(acc), s2 = wred(acc * acc);
      if (lane == 0) { red[w*2] = s1; red[w*2+1] = s2; }
      __syncthreads();
      float S = 0, Q = 0;
#pragma unroll
      for (int i = 0; i < 16; ++i) { S += red[i*2]; Q += red[i*2+1]; }
      float mn = S / DD, vr = fmaxf(Q / DD - mn * mn, 0.f);
      val[tid] = (acc - mn) * rsqrtf(vr + EPS) * lno_g[tid] + lno_b[tid];
      __syncthreads();
    }
    {
      float gt_ = gate[(size_t)b * LINES + t];
      float vv = val[tid];
#pragma unroll 4
      for (int r = 0; r < NREG; ++r) {
        float gg = gt_ * wv[r];
        size_t idx = (size_t)r * DD + tid;
        Rb[idx] = Rb[idx] * (1.f - gg) + gg * vv;
      }
    }
    __syncthreads();
  }
}

extern "C" void kernel_launch(void* const* d_in, const int* in_sizes, int n_in,
                              void* d_out, int out_size, void* d_ws, size_t ws_size,
                              hipStream_t stream) {
  const float* opcode = (const float*)d_in[0];
  const float* registers = (const float*)d_in[1];
  const float* k_write = (const float*)d_in[2];
  const float* q_read = (const float*)d_in[3];
  const float* gate = (const float*)d_in[5];
  const float* ln1_g = (const float*)d_in[6];
  const float* ln1_b = (const float*)d_in[7];
  const float* w1 = (const float*)d_in[8];
  const float* b1 = (const float*)d_in[9];
  const float* ln2_g = (const float*)d_in[10];
  const float* ln2_b = (const float*)d_in[11];
  const float* w2 = (const float*)d_in[12];
  const float* b2 = (const float*)d_in[13];
  const float* w_res = (const float*)d_in[14];
  const float* b_res = (const float*)d_in[15];
  const float* lno_g = (const float*)d_in[16];
  const float* lno_b = (const float*)d_in[17];
  float* R = (float*)d_out;

  if (ws_size >= (size_t)WS_NEED) {
    transcvt<<<dim3(16, 16, 3), 256, 0, stream>>>(w1, w2, w_res, (bf16_t*)d_ws);
    hipMemsetAsync((char*)d_ws + WS_CTR, 0, 1024, stream);
    interp3<<<BB, 1024, 0, stream>>>(opcode, registers, k_write, q_read, gate,
                                     ln1_g, ln1_b, b1, ln2_g, ln2_b, b2,
                                     b_res, lno_g, lno_b, (char*)d_ws, R);
  } else {
    hipMemcpyAsync(R, registers, (size_t)BB * NREG * DD * sizeof(float),
                   hipMemcpyDeviceToDevice, stream);
    interp_fb<<<BB, 1024, 0, stream>>>(opcode, k_write, q_read, gate, ln1_g, ln1_b,
                                       w1, b1, ln2_g, ln2_b, w2, b2, w_res, b_res,
                                       lno_g, lno_b, R);
  }
}